// Round 10
// baseline (769.070 us; speedup 1.0000x reference)
//
#include <hip/hip_runtime.h>
#include <stdint.h>

// RNN-T prediction network: embed lookup + 2-layer LSTM, U=128, N=512, C=320.
// FP32 in/out; internal GEMMs bf16 MFMA + fp32 accumulate.
// Persistent cooperative kernel, 256 WGs = 16 batch-groups x 16 hidden-groups.
// R14: dual half-tick schedule. R13 showed no single exposed bubble remains;
//      the tick is a sum of phases x 6 barriers. Split each tick into two
//      independent sub-ticks over rows 0-15 (A) and 16-31 (B) -- exactly the
//      ag00/ag01 halves of the R13 fragments, so all fragment/staging math is
//      verbatim. Per tick: GEMM-A (fused 3-matrix, 30 MFMA/wave) -> B1 ->
//      pw-A + flagA publish -> GEMM-B -> B2 -> pw-B + flagB publish ->
//      pollA (gap ~2.5k cy, covered) -> B3 -> stageA -> pollB -> B4 -> stageB.
//      4 barriers (was 6), polls covered by half-tick gaps, pw = 1 unit/thread.
//      Proven invariants kept: grid=256 (512 never launches), sc0 one-shot
//      data at XCD L2 (runtime-gated fail-safe), flags agent-scope IC only.

typedef short short8 __attribute__((ext_vector_type(8)));
typedef float f32x4 __attribute__((ext_vector_type(4)));
typedef unsigned long long u64t;

#define USTEPS 128
#define HSZ    (512*320)
#define GSTEP  (512*320)
#define HGOFF  (128*512*320)
#define CGOFF  (HGOFF + 2*512*320)
#define FLAGSTRIDE 16   // uint32s = 64B per slot

__device__ __forceinline__ uint16_t f2bf(float f) {
  union { float f; uint32_t i; } v; v.f = f;
  uint32_t i = v.i;
  return (uint16_t)((i + 0x7fffu + ((i >> 16) & 1u)) >> 16);
}
__device__ __forceinline__ float rcp_(float x) { return __builtin_amdgcn_rcpf(x); }
__device__ __forceinline__ float sigm(float x) { return rcp_(1.0f + __expf(-x)); }
__device__ __forceinline__ float tanh_(float x) {
  float ax = fabsf(x);
  float e  = __expf(-2.0f * ax);
  float t  = (1.0f - e) * rcp_(1.0f + e);
  return x < 0.0f ? -t : t;
}
__device__ __forceinline__ uint4 cvt8(const float* s) {
  float4 a = ((const float4*)s)[0];
  float4 b = ((const float4*)s)[1];
  uint4 r;
  r.x = (uint32_t)f2bf(a.x) | ((uint32_t)f2bf(a.y) << 16);
  r.y = (uint32_t)f2bf(a.z) | ((uint32_t)f2bf(a.w) << 16);
  r.z = (uint32_t)f2bf(b.x) | ((uint32_t)f2bf(b.y) << 16);
  r.w = (uint32_t)f2bf(b.z) | ((uint32_t)f2bf(b.w) << 16);
  return r;
}
__device__ __forceinline__ short8 loadw8(const float* p) {
  float4 a = ((const float4*)p)[0];
  float4 b = ((const float4*)p)[1];
  short8 r;
  r[0] = (short)f2bf(a.x); r[1] = (short)f2bf(a.y);
  r[2] = (short)f2bf(a.z); r[3] = (short)f2bf(a.w);
  r[4] = (short)f2bf(b.x); r[5] = (short)f2bf(b.y);
  r[6] = (short)f2bf(b.z); r[7] = (short)f2bf(b.w);
  return r;
}

// ---- scope-selectable one-shot data-exchange ops (R8-proven) --------------
__device__ __forceinline__ u64t slowld64(const void* p) {
  return __hip_atomic_load((const u64t*)p, __ATOMIC_RELAXED,
                           __HIP_MEMORY_SCOPE_AGENT);
}
template<bool FAST>
__device__ __forceinline__ u64t exld64(const void* p) {
  if (FAST) {
    u64t r;
    asm volatile("global_load_dwordx2 %0, %1, off sc0" : "=v"(r) : "v"(p));
    return r;
  } else {
    return slowld64(p);
  }
}
template<bool FAST>
__device__ __forceinline__ void exst32(void* p, uint32_t v) {
  if (FAST) {
    asm volatile("global_store_dword %0, %1, off sc0" :: "v"(p), "v"(v) : "memory");
  } else {
    __hip_atomic_store((uint32_t*)p, v, __ATOMIC_RELAXED,
                       __HIP_MEMORY_SCOPE_AGENT);
  }
}
__device__ __forceinline__ void vm_drain() {
  asm volatile("s_waitcnt vmcnt(0)" ::: "memory");
}

// ---------------------------------------------------------------------------
// prep: G0p table, bias1p, flag+xcdtab zeroing, h0 -> bf16 prefill of
// exchange slot 1 for both layers. (R13 verbatim)
// ---------------------------------------------------------------------------
#define PREP_G0   (29 * 1280)
#define PREP_B1   (PREP_G0 + 1280)
#define PREP_FL   (PREP_B1 + 8448)          // 2*4096 flags + 256 xcdtab
#define PREP_HI   (PREP_FL + 2 * 512 * 40)  // 40960 cvt8 items
__global__ void prep_kernel(const float* __restrict__ embed,
                            const float* __restrict__ w_ih,
                            const float* __restrict__ b_ih,
                            const float* __restrict__ b_hh,
                            const float* __restrict__ h0,
                            float* __restrict__ G0p,
                            float* __restrict__ bias1p,
                            uint32_t* __restrict__ flags,
                            uint16_t* __restrict__ Hx0,
                            uint16_t* __restrict__ Hx1) {
  int tid = blockIdx.x * blockDim.x + threadIdx.x;
  if (tid < PREP_G0) {
    int v = tid / 1280, col = tid % 1280;
    int hg = col / 80, idx = col % 80;
    int k = idx >> 2, q = idx & 3;
    int r = q * 320 + hg * 20 + k;
    float acc = b_ih[r] + b_hh[r];
    if (v < 28) {
      const float4* e = (const float4*)(embed + (size_t)v * 320);
      const float4* w = (const float4*)(w_ih + (size_t)r * 320);
#pragma unroll 4
      for (int i = 0; i < 80; ++i) {
        float4 a = e[i], b = w[i];
        acc += a.x * b.x + a.y * b.y + a.z * b.z + a.w * b.w;
      }
    }
    G0p[tid] = acc;
  } else if (tid < PREP_B1) {
    int col = tid - PREP_G0;
    int hg = col / 80, idx = col % 80;
    int k = idx >> 2, q = idx & 3;
    int r = q * 320 + hg * 20 + k;
    bias1p[col] = b_ih[1280 + r] + b_hh[1280 + r];
  } else if (tid < PREP_FL) {
    flags[tid - PREP_B1] = 0;
  } else if (tid < PREP_HI) {
    int id = tid - PREP_FL;              // 0..40959, 8 elements each
    int layer = id / 20480;
    int rem = id - layer * 20480;        // n*40 + c
    int n = rem / 40, c = rem - n * 40;
    const float* src = h0 + (size_t)layer * HSZ + (size_t)n * 320 + c * 8;
    uint16_t* dst = (layer ? Hx1 : Hx0) + HSZ + (size_t)n * 320 + c * 8;
    *(uint4*)dst = cvt8(src);
  }
}

// ---------------------------------------------------------------------------
// main loop body, templated on data-exchange scope (flags always agent/IC)
// ---------------------------------------------------------------------------
template<bool FAST>
__device__ __forceinline__ void run_loop(
    const int* __restrict__ x, const float* __restrict__ c0,
    const float* __restrict__ w_ih, const float* __restrict__ w_hh,
    const float* __restrict__ G0p, const float* __restrict__ bias1p,
    uint16_t* __restrict__ Hx0, uint16_t* __restrict__ Hx1,
    uint32_t* __restrict__ flags, float* __restrict__ out,
    uint16_t* Hl0, uint16_t* Hl1,
    float* g0A, float* g1A, float* g0B, float* g1B,
    int* ctrA, int* ctrB) {
  const int tid  = threadIdx.x;
  const int wave = tid >> 6;
  const int lane = tid & 63;
  const int quad = lane >> 4;
  const int lm   = lane & 15;
  const int blk  = blockIdx.x;
  const int bg = (blk & 7) * 2 + (blk >> 7);
  const int hg = (blk >> 3) & 15;

  // ---- persistent weight fragments (bf16): wave owns 16 gate-cols (R13)
  short8 Bhh0[10], Bih1[10], Bhh1[10];
  {
    int ncol = wave * 16 + lm;       // local col 0..79 (= 4k+q)
    int k = ncol >> 2, q = ncol & 3;
    int r = q * 320 + hg * 20 + k;   // original gate row
    const float* p0 = w_hh + (size_t)r * 320 + quad * 8;
    const float* p1 = w_hh + (size_t)(1280 + r) * 320 + quad * 8;
    const float* pi = w_ih + (size_t)(1280 + r) * 320 + quad * 8;
#pragma unroll
    for (int kk = 0; kk < 10; ++kk) {
      Bhh0[kk] = loadw8(p0 + kk * 32);
      Bhh1[kk] = loadw8(p1 + kk * 32);
      Bih1[kk] = loadw8(pi + kk * 32);
    }
  }
  const float bias1v = bias1p[hg * 80 + wave * 16 + lm];

  // ---- pointwise mapping: 1 unit/thread. un2 = row-in-sub, uk = unit 0..19
  const int un2 = tid / 20;
  const int uk  = tid - un2 * 20;
  const int bA  = bg * 32 + un2;        // sub-A global row
  const int bB  = bA + 16;              // sub-B global row
  const int kc  = hg * 20 + uk;
  const bool ukeven = (uk & 1) == 0;

  // ---- staging address precompute (R13 verbatim; it 0..3 = rows 0..15 (A),
  //      it 4..7 = rows 16..31 (B))
  int smc[8], spc[8];
#pragma unroll
  for (int it = 0; it < 8; ++it) {
    int cid = tid + it * 320;
    int m = cid / 80;
    int c8 = cid - m * 80;
    int c16 = c8 >> 1, h = c8 & 1;
    int p16 = c16 + m; if (p16 >= 40) p16 -= 40;
    smc[it] = m * 320 + c8 * 4;
    spc[it] = m * 320 + p16 * 8 + h * 4;
  }
  const size_t gbase = (size_t)bg * 32 * 320;

  float cA0 = c0[(size_t)bA * 320 + kc];
  float cA1 = c0[(size_t)(512 + bA) * 320 + kc];
  float cB0 = c0[(size_t)bB * 320 + kc];
  float cB1 = c0[(size_t)(512 + bB) * 320 + kc];

  uint32_t* flagsA  = flags;
  uint32_t* flagsB  = flags + 256 * FLAGSTRIDE;
  uint32_t* myflagA = flagsA + (size_t)(bg * 16 + hg) * FLAGSTRIDE;
  uint32_t* myflagB = flagsB + (size_t)(bg * 16 + hg) * FLAGSTRIDE;

  // ---- pre-stage Hl0 (both halves) <- initial h0 (prep slot 1): slow/IC
  {
    const uint16_t* s0b = Hx0 + HSZ + gbase;
    u64t r0[8];
#pragma unroll
    for (int it = 0; it < 8; ++it) r0[it] = slowld64(s0b + smc[it]);
    vm_drain();
#pragma unroll
    for (int it = 0; it < 8; ++it) *(u64t*)(Hl0 + spc[it]) = r0[it];
    __syncthreads();
  }

  // ---- prefetch x/G0p gates for tick 0 (one float4 per sub per thread)
  float4 gxA, gxB;
  {
    const int vA = x[bA];
    const int vB = x[bB];
    gxA = *(const float4*)(G0p + (size_t)vA * 1280 + hg * 80 + uk * 4);
    gxB = *(const float4*)(G0p + (size_t)vB * 1280 + hg * 80 + uk * 4);
  }

#pragma unroll 1
  for (int t = 0; t <= USTEPS; ++t) {
    const bool do0 = (t < USTEPS);   // layer0 computes h0[t]
    const bool do1 = (t >= 1);       // layer1 computes h1[t-1]

    // ================= SUB A (rows 0..15) =================
    {
      f32x4 a0 = {0.f, 0.f, 0.f, 0.f};
      f32x4 a1 = {bias1v, bias1v, bias1v, bias1v};
#pragma unroll
      for (int kk = 0; kk < 10; ++kk) {
        int cch = kk * 4 + quad;
        int p = cch + lm; if (p >= 40) p -= 40;
        short8 h0f = *(const short8*)(Hl0 + lm * 320 + p * 8);
        short8 h1f = *(const short8*)(Hl1 + lm * 320 + p * 8);
        if (do0)
          a0 = __builtin_amdgcn_mfma_f32_16x16x32_bf16(h0f, Bhh0[kk], a0, 0, 0, 0);
        if (do1) {
          a1 = __builtin_amdgcn_mfma_f32_16x16x32_bf16(h0f, Bih1[kk], a1, 0, 0, 0);
          a1 = __builtin_amdgcn_mfma_f32_16x16x32_bf16(h1f, Bhh1[kk], a1, 0, 0, 0);
        }
      }
#pragma unroll
      for (int r = 0; r < 4; ++r) {
        g0A[(quad * 4 + r) * 84 + wave * 16 + lm] = a0[r];
        g1A[(quad * 4 + r) * 84 + wave * 16 + lm] = a1[r];
      }
    }
    __syncthreads();                                   // B1

    // ---- pw-A (1 unit/thread)
    {
      float4 g0 = *(const float4*)(g0A + un2 * 84 + uk * 4);
      float4 g1 = *(const float4*)(g1A + un2 * 84 + uk * 4);
      float h0v = 0.f, h1v = 0.f;
      if (do0) {
        float i = sigm(g0.x + gxA.x), f = sigm(g0.y + gxA.y);
        float g = tanh_(g0.z + gxA.z), o = sigm(g0.w + gxA.w);
        cA0 = f * cA0 + i * g;
        h0v = o * tanh_(cA0);
      }
      if (do1) {
        float i = sigm(g1.x), f = sigm(g1.y);
        float g = tanh_(g1.z), o = sigm(g1.w);
        cA1 = f * cA1 + i * g;
        h1v = o * tanh_(cA1);
      }
      float h0p = __shfl_down(h0v, 1);
      float h1p = __shfl_down(h1v, 1);
      if (do0 && ukeven) {
        uint32_t pk = (uint32_t)f2bf(h0v) | ((uint32_t)f2bf(h0p) << 16);
        exst32<FAST>(Hx0 + (size_t)(t & 1) * HSZ + (size_t)bA * 320 + kc, pk);
      }
      if (do1 && ukeven) {
        uint32_t pk = (uint32_t)f2bf(h1v) | ((uint32_t)f2bf(h1p) << 16);
        exst32<FAST>(Hx1 + (size_t)((t + 1) & 1) * HSZ + (size_t)bA * 320 + kc, pk);
      }
      vm_drain();
      if (t < USTEPS && lane == 0) {
        int old = atomicAdd(ctrA, 1);
        if ((old % 5) == 4)
          __hip_atomic_store(myflagA, (uint32_t)(t + 1), __ATOMIC_RELAXED,
                             __HIP_MEMORY_SCOPE_AGENT);
      }
      // off-critical-path stores after publish
      if (do1 && ukeven)
        *(float2*)(out + (size_t)(t - 1) * GSTEP + (size_t)bA * 320 + kc) =
            make_float2(h1v, h1p);
      float c0p = __shfl_down(cA0, 1);
      float c1p = __shfl_down(cA1, 1);
      if (do0 && t == USTEPS - 1 && ukeven) {
        *(float2*)(out + HGOFF + (size_t)bA * 320 + kc) = make_float2(h0v, h0p);
        *(float2*)(out + CGOFF + (size_t)bA * 320 + kc) = make_float2(cA0, c0p);
      }
      if (t == USTEPS && ukeven) {
        *(float2*)(out + HGOFF + (size_t)(512 + bA) * 320 + kc) = make_float2(h1v, h1p);
        *(float2*)(out + CGOFF + (size_t)(512 + bA) * 320 + kc) = make_float2(cA1, c1p);
      }
    }

    // ================= SUB B (rows 16..31) =================
    {
      f32x4 a0 = {0.f, 0.f, 0.f, 0.f};
      f32x4 a1 = {bias1v, bias1v, bias1v, bias1v};
#pragma unroll
      for (int kk = 0; kk < 10; ++kk) {
        int cch = kk * 4 + quad;
        int p = cch + lm + 16; if (p >= 40) p -= 40;
        short8 h0f = *(const short8*)(Hl0 + (lm + 16) * 320 + p * 8);
        short8 h1f = *(const short8*)(Hl1 + (lm + 16) * 320 + p * 8);
        if (do0)
          a0 = __builtin_amdgcn_mfma_f32_16x16x32_bf16(h0f, Bhh0[kk], a0, 0, 0, 0);
        if (do1) {
          a1 = __builtin_amdgcn_mfma_f32_16x16x32_bf16(h0f, Bih1[kk], a1, 0, 0, 0);
          a1 = __builtin_amdgcn_mfma_f32_16x16x32_bf16(h1f, Bhh1[kk], a1, 0, 0, 0);
        }
      }
#pragma unroll
      for (int r = 0; r < 4; ++r) {
        g0B[(quad * 4 + r) * 84 + wave * 16 + lm] = a0[r];
        g1B[(quad * 4 + r) * 84 + wave * 16 + lm] = a1[r];
      }
    }
    __syncthreads();                                   // B2

    // ---- pw-B
    {
      float4 g0 = *(const float4*)(g0B + un2 * 84 + uk * 4);
      float4 g1 = *(const float4*)(g1B + un2 * 84 + uk * 4);
      float h0v = 0.f, h1v = 0.f;
      if (do0) {
        float i = sigm(g0.x + gxB.x), f = sigm(g0.y + gxB.y);
        float g = tanh_(g0.z + gxB.z), o = sigm(g0.w + gxB.w);
        cB0 = f * cB0 + i * g;
        h0v = o * tanh_(cB0);
      }
      if (do1) {
        float i = sigm(g1.x), f = sigm(g1.y);
        float g = tanh_(g1.z), o = sigm(g1.w);
        cB1 = f * cB1 + i * g;
        h1v = o * tanh_(cB1);
      }
      float h0p = __shfl_down(h0v, 1);
      float h1p = __shfl_down(h1v, 1);
      if (do0 && ukeven) {
        uint32_t pk = (uint32_t)f2bf(h0v) | ((uint32_t)f2bf(h0p) << 16);
        exst32<FAST>(Hx0 + (size_t)(t & 1) * HSZ + (size_t)bB * 320 + kc, pk);
      }
      if (do1 && ukeven) {
        uint32_t pk = (uint32_t)f2bf(h1v) | ((uint32_t)f2bf(h1p) << 16);
        exst32<FAST>(Hx1 + (size_t)((t + 1) & 1) * HSZ + (size_t)bB * 320 + kc, pk);
      }
      vm_drain();
      if (t < USTEPS && lane == 0) {
        int old = atomicAdd(ctrB, 1);
        if ((old % 5) == 4)
          __hip_atomic_store(myflagB, (uint32_t)(t + 1), __ATOMIC_RELAXED,
                             __HIP_MEMORY_SCOPE_AGENT);
      }
      if (do1 && ukeven)
        *(float2*)(out + (size_t)(t - 1) * GSTEP + (size_t)bB * 320 + kc) =
            make_float2(h1v, h1p);
      float c0p = __shfl_down(cB0, 1);
      float c1p = __shfl_down(cB1, 1);
      if (do0 && t == USTEPS - 1 && ukeven) {
        *(float2*)(out + HGOFF + (size_t)bB * 320 + kc) = make_float2(h0v, h0p);
        *(float2*)(out + CGOFF + (size_t)bB * 320 + kc) = make_float2(cB0, c0p);
      }
      if (t == USTEPS && ukeven) {
        *(float2*)(out + HGOFF + (size_t)(512 + bB) * 320 + kc) = make_float2(h1v, h1p);
        *(float2*)(out + CGOFF + (size_t)(512 + bB) * 320 + kc) = make_float2(cB1, c1p);
      }
    }

    // ---- prefetch next tick's x/G0p gates (both subs)
    if (t + 1 < USTEPS) {
      const int vA = x[(t + 1) * 512 + bA];
      const int vB = x[(t + 1) * 512 + bB];
      gxA = *(const float4*)(G0p + (size_t)vA * 1280 + hg * 80 + uk * 4);
      gxB = *(const float4*)(G0p + (size_t)vB * 1280 + hg * 80 + uk * 4);
    }

    // ---- tick end: pollA (gap ~GEMM-B+pw-B, covered) -> stageA -> pollB
    //      (gap += stageA) -> stageB
    if (t < USTEPS) {
      if (tid < 16) {
        uint32_t* peer = flagsA + (size_t)(bg * 16 + tid) * FLAGSTRIDE;
        while (__hip_atomic_load(peer, __ATOMIC_RELAXED,
                                 __HIP_MEMORY_SCOPE_AGENT) < (uint32_t)(t + 1)) {
        }
      }
      __syncthreads();                                 // B3
      {
        const uint16_t* s0b = Hx0 + (size_t)(t & 1) * HSZ + gbase;
        const uint16_t* s1b = Hx1 + (size_t)((t + 1) & 1) * HSZ + gbase;
        u64t r0[4], r1[4];
#pragma unroll
        for (int it = 0; it < 4; ++it) r0[it] = exld64<FAST>(s0b + smc[it]);
        if (FAST && t == 0) {
#pragma unroll
          for (int it = 0; it < 4; ++it) r1[it] = slowld64(s1b + smc[it]);
        } else {
#pragma unroll
          for (int it = 0; it < 4; ++it) r1[it] = exld64<FAST>(s1b + smc[it]);
        }
        vm_drain();
#pragma unroll
        for (int it = 0; it < 4; ++it) {
          *(u64t*)(Hl0 + spc[it]) = r0[it];
          *(u64t*)(Hl1 + spc[it]) = r1[it];
        }
      }
      if (tid < 16) {
        uint32_t* peer = flagsB + (size_t)(bg * 16 + tid) * FLAGSTRIDE;
        while (__hip_atomic_load(peer, __ATOMIC_RELAXED,
                                 __HIP_MEMORY_SCOPE_AGENT) < (uint32_t)(t + 1)) {
        }
      }
      __syncthreads();                                 // B4
      {
        const uint16_t* s0b = Hx0 + (size_t)(t & 1) * HSZ + gbase;
        const uint16_t* s1b = Hx1 + (size_t)((t + 1) & 1) * HSZ + gbase;
        u64t r0[4], r1[4];
#pragma unroll
        for (int it = 4; it < 8; ++it) r0[it - 4] = exld64<FAST>(s0b + smc[it]);
        if (FAST && t == 0) {
#pragma unroll
          for (int it = 4; it < 8; ++it) r1[it - 4] = slowld64(s1b + smc[it]);
        } else {
#pragma unroll
          for (int it = 4; it < 8; ++it) r1[it - 4] = exld64<FAST>(s1b + smc[it]);
        }
        vm_drain();
#pragma unroll
        for (int it = 4; it < 8; ++it) {
          *(u64t*)(Hl0 + spc[it]) = r0[it - 4];
          *(u64t*)(Hl1 + spc[it]) = r1[it - 4];
        }
      }
      // stageB's LDS writes are ordered before GEMM-B(t+1) reads by B1(t+1);
      // GEMM-A(t+1) touches only rows 0..15 (disjoint).
    }
  }
}

// ---------------------------------------------------------------------------
// main persistent kernel: fail-safe XCD handshake (R13 verbatim), scoped loop
// ---------------------------------------------------------------------------
__global__ void __launch_bounds__(320, 2)
rnnt_kernel(const int* __restrict__ x,
            const float* __restrict__ c0,
            const float* __restrict__ w_ih,
            const float* __restrict__ w_hh,
            const float* __restrict__ G0p,
            const float* __restrict__ bias1p,
            uint16_t* __restrict__ Hx0,
            uint16_t* __restrict__ Hx1,
            uint32_t* __restrict__ flags,
            float* __restrict__ out) {
  __shared__ __align__(16) uint16_t Hl0[32 * 320];
  __shared__ __align__(16) uint16_t Hl1[32 * 320];
  __shared__ __align__(16) float    g0A[16 * 84];
  __shared__ __align__(16) float    g1A[16 * 84];
  __shared__ __align__(16) float    g0B[16 * 84];
  __shared__ __align__(16) float    g1B[16 * 84];
  __shared__ int ctrA, ctrB;
  __shared__ uint32_t v0sh;

  const int tid = threadIdx.x;
  const int blk = blockIdx.x;
  const int bg = (blk & 7) * 2 + (blk >> 7);
  const int hg = (blk >> 3) & 15;

  // XCC probe: hwreg(id=20, offset=0, size=4) = 20 | (3<<11). Garbage or
  // per-CU-varying reads force the slow path via the checks below (safe).
  const uint32_t xcc = (uint32_t)__builtin_amdgcn_s_getreg((3 << 11) | 20) & 0xffu;
  const uint32_t mine = 0x100u | xcc;
  uint32_t* xcdtab = flags + 8192;

  if (tid == 0) {
    ctrA = 0; ctrB = 0;
    __hip_atomic_store(&xcdtab[bg * 16 + hg], mine, __ATOMIC_RELAXED,
                       __HIP_MEMORY_SCOPE_AGENT);
  }
  uint32_t v = 0;
  if (tid < 256) {
    do {
      v = __hip_atomic_load(&xcdtab[tid], __ATOMIC_RELAXED,
                            __HIP_MEMORY_SCOPE_AGENT);
    } while (v == 0u);
    if (tid == 0) v0sh = v;
  }
  __syncthreads();
  const uint32_t v0 = v0sh;
  const int anydiff = __syncthreads_or((tid < 256) ? (int)(v != v0) : 0);
  const int anybad  = __syncthreads_or(
      (tid < 256 && (tid >> 4) == bg) ? (int)(v != mine) : 0);
  const bool fastok = (anydiff != 0) && (anybad == 0);

  if (fastok)
    run_loop<true>(x, c0, w_ih, w_hh, G0p, bias1p, Hx0, Hx1, flags, out,
                   Hl0, Hl1, g0A, g1A, g0B, g1B, &ctrA, &ctrB);
  else
    run_loop<false>(x, c0, w_ih, w_hh, G0p, bias1p, Hx0, Hx1, flags, out,
                    Hl0, Hl1, g0A, g1A, g0B, g1B, &ctrA, &ctrB);
}

extern "C" void kernel_launch(void* const* d_in, const int* in_sizes, int n_in,
                              void* d_out, int out_size, void* d_ws, size_t ws_size,
                              hipStream_t stream) {
  (void)in_sizes; (void)n_in; (void)out_size; (void)ws_size;
  const int*   x     = (const int*)d_in[0];
  const float* h0    = (const float*)d_in[1];
  const float* c0    = (const float*)d_in[2];
  const float* embed = (const float*)d_in[3];
  const float* w_ih  = (const float*)d_in[4];
  const float* w_hh  = (const float*)d_in[5];
  const float* b_ih  = (const float*)d_in[6];
  const float* b_hh  = (const float*)d_in[7];
  float* out = (float*)d_out;

  char* ws = (char*)d_ws;
  float*    G0p   = (float*)(ws);              // 29*1280*4   = 148480 B
  float*    b1p   = (float*)(ws + 148480);     // 1280*4      =   5120 B
  uint32_t* flags = (uint32_t*)(ws + 153600);  // 8448*4      =  33792 B
  uint16_t* Hx0   = (uint16_t*)(ws + 187392);  // 2*512*320*2 = 655360 B
  uint16_t* Hx1   = (uint16_t*)(ws + 842752);  // 2*512*320*2 = 655360 B

  hipLaunchKernelGGL(prep_kernel, dim3((PREP_HI + 255) / 256), dim3(256), 0,
                     stream, embed, w_ih, b_ih, b_hh, h0, G0p, b1p, flags,
                     Hx0, Hx1);

  void* args[] = { (void*)&x, (void*)&c0, (void*)&w_ih, (void*)&w_hh,
                   (void*)&G0p, (void*)&b1p, (void*)&Hx0, (void*)&Hx1,
                   (void*)&flags, (void*)&out };
  hipLaunchCooperativeKernel((const void*)rnnt_kernel, dim3(256), dim3(320),
                             args, 0, stream);
}

// Round 11
// 719.726 us; speedup vs baseline: 1.0686x; 1.0686x over previous
//
#include <hip/hip_runtime.h>
#include <stdint.h>

// RNN-T prediction network: embed lookup + 2-layer LSTM, U=128, N=512, C=320.
// FP32 in/out; internal GEMMs bf16 MFMA + fp32 accumulate.
// Persistent cooperative kernel, 256 WGs = 16 batch-groups x 16 hidden-groups.
// R15: R13 (best, 602us) + two surgical fixes, no structural change.
//      (1) gates pitch 84->85 words (odd): the float4 gates reads at 8-word
//          stride with even pitch start at only 4 banks {0,8,16,24} per
//          un-group -> ~2x LDS cost; odd pitch spreads groups by 21 banks.
//          Signature: SQ_LDS_BANK_CONFLICT 2.88e7 -> ~1.5-2.2e7.
//      (2) B0..B1 window reorder: issue Hl1 loads -> write gates0 (covers
//          part of the load RT) -> drain -> write Hl1. R8-proven pattern.
//      Proven invariants: grid=256 (512 never launches), sc0 one-shot data
//      at XCD L2 (runtime-gated fail-safe), flags agent-scope IC only
//      (sc0 spin-polls hang), R8 32-row geometry verbatim.

typedef short short8 __attribute__((ext_vector_type(8)));
typedef float f32x4 __attribute__((ext_vector_type(4)));
typedef unsigned long long u64t;

#define USTEPS 128
#define HSZ    (512*320)
#define GSTEP  (512*320)
#define HGOFF  (128*512*320)
#define CGOFF  (HGOFF + 2*512*320)
#define FLAGSTRIDE 16   // uint32s = 64B per slot
#define GSTRIDE 85      // gates row pitch in floats (odd -> bank spread)

__device__ __forceinline__ uint16_t f2bf(float f) {
  union { float f; uint32_t i; } v; v.f = f;
  uint32_t i = v.i;
  return (uint16_t)((i + 0x7fffu + ((i >> 16) & 1u)) >> 16);
}
__device__ __forceinline__ float rcp_(float x) { return __builtin_amdgcn_rcpf(x); }
__device__ __forceinline__ float sigm(float x) { return rcp_(1.0f + __expf(-x)); }
__device__ __forceinline__ float tanh_(float x) {
  float ax = fabsf(x);
  float e  = __expf(-2.0f * ax);
  float t  = (1.0f - e) * rcp_(1.0f + e);
  return x < 0.0f ? -t : t;
}
__device__ __forceinline__ uint4 cvt8(const float* s) {
  float4 a = ((const float4*)s)[0];
  float4 b = ((const float4*)s)[1];
  uint4 r;
  r.x = (uint32_t)f2bf(a.x) | ((uint32_t)f2bf(a.y) << 16);
  r.y = (uint32_t)f2bf(a.z) | ((uint32_t)f2bf(a.w) << 16);
  r.z = (uint32_t)f2bf(b.x) | ((uint32_t)f2bf(b.y) << 16);
  r.w = (uint32_t)f2bf(b.z) | ((uint32_t)f2bf(b.w) << 16);
  return r;
}
__device__ __forceinline__ short8 loadw8(const float* p) {
  float4 a = ((const float4*)p)[0];
  float4 b = ((const float4*)p)[1];
  short8 r;
  r[0] = (short)f2bf(a.x); r[1] = (short)f2bf(a.y);
  r[2] = (short)f2bf(a.z); r[3] = (short)f2bf(a.w);
  r[4] = (short)f2bf(b.x); r[5] = (short)f2bf(b.y);
  r[6] = (short)f2bf(b.z); r[7] = (short)f2bf(b.w);
  return r;
}

// ---- scope-selectable one-shot data-exchange ops (R8-proven) --------------
__device__ __forceinline__ u64t slowld64(const void* p) {
  return __hip_atomic_load((const u64t*)p, __ATOMIC_RELAXED,
                           __HIP_MEMORY_SCOPE_AGENT);
}
template<bool FAST>
__device__ __forceinline__ u64t exld64(const void* p) {
  if (FAST) {
    u64t r;
    asm volatile("global_load_dwordx2 %0, %1, off sc0" : "=v"(r) : "v"(p));
    return r;
  } else {
    return slowld64(p);
  }
}
template<bool FAST>
__device__ __forceinline__ void exst32(void* p, uint32_t v) {
  if (FAST) {
    asm volatile("global_store_dword %0, %1, off sc0" :: "v"(p), "v"(v) : "memory");
  } else {
    __hip_atomic_store((uint32_t*)p, v, __ATOMIC_RELAXED,
                       __HIP_MEMORY_SCOPE_AGENT);
  }
}
__device__ __forceinline__ void vm_drain() {
  asm volatile("s_waitcnt vmcnt(0)" ::: "memory");
}

// ---------------------------------------------------------------------------
// prep: G0p table, bias1p, flag+xcdtab zeroing, h0 -> bf16 prefill of
// exchange slot 1 for both layers. (R13 verbatim)
// ---------------------------------------------------------------------------
#define PREP_G0   (29 * 1280)
#define PREP_B1   (PREP_G0 + 1280)
#define PREP_FL   (PREP_B1 + 8448)          // 2*4096 flags + 256 xcdtab
#define PREP_HI   (PREP_FL + 2 * 512 * 40)  // 40960 cvt8 items
__global__ void prep_kernel(const float* __restrict__ embed,
                            const float* __restrict__ w_ih,
                            const float* __restrict__ b_ih,
                            const float* __restrict__ b_hh,
                            const float* __restrict__ h0,
                            float* __restrict__ G0p,
                            float* __restrict__ bias1p,
                            uint32_t* __restrict__ flags,
                            uint16_t* __restrict__ Hx0,
                            uint16_t* __restrict__ Hx1) {
  int tid = blockIdx.x * blockDim.x + threadIdx.x;
  if (tid < PREP_G0) {
    int v = tid / 1280, col = tid % 1280;
    int hg = col / 80, idx = col % 80;
    int k = idx >> 2, q = idx & 3;
    int r = q * 320 + hg * 20 + k;
    float acc = b_ih[r] + b_hh[r];
    if (v < 28) {
      const float4* e = (const float4*)(embed + (size_t)v * 320);
      const float4* w = (const float4*)(w_ih + (size_t)r * 320);
#pragma unroll 4
      for (int i = 0; i < 80; ++i) {
        float4 a = e[i], b = w[i];
        acc += a.x * b.x + a.y * b.y + a.z * b.z + a.w * b.w;
      }
    }
    G0p[tid] = acc;
  } else if (tid < PREP_B1) {
    int col = tid - PREP_G0;
    int hg = col / 80, idx = col % 80;
    int k = idx >> 2, q = idx & 3;
    int r = q * 320 + hg * 20 + k;
    bias1p[col] = b_ih[1280 + r] + b_hh[1280 + r];
  } else if (tid < PREP_FL) {
    flags[tid - PREP_B1] = 0;
  } else if (tid < PREP_HI) {
    int id = tid - PREP_FL;              // 0..40959, 8 elements each
    int layer = id / 20480;
    int rem = id - layer * 20480;        // n*40 + c
    int n = rem / 40, c = rem - n * 40;
    const float* src = h0 + (size_t)layer * HSZ + (size_t)n * 320 + c * 8;
    uint16_t* dst = (layer ? Hx1 : Hx0) + HSZ + (size_t)n * 320 + c * 8;
    *(uint4*)dst = cvt8(src);
  }
}

// ---------------------------------------------------------------------------
// main loop body, templated on data-exchange scope (flags always agent/IC)
// ---------------------------------------------------------------------------
template<bool FAST>
__device__ __forceinline__ void run_loop(
    const int* __restrict__ x, const float* __restrict__ c0,
    const float* __restrict__ w_ih, const float* __restrict__ w_hh,
    const float* __restrict__ G0p, const float* __restrict__ bias1p,
    uint16_t* __restrict__ Hx0, uint16_t* __restrict__ Hx1,
    uint32_t* __restrict__ flags, float* __restrict__ out,
    uint16_t* Hl0, uint16_t* Hl1, float* gates0, float* gates1,
    int* ctr0, int* ctr1) {
  const int tid  = threadIdx.x;
  const int wave = tid >> 6;
  const int lane = tid & 63;
  const int quad = lane >> 4;
  const int lm   = lane & 15;
  const int blk  = blockIdx.x;
  const int bg = (blk & 7) * 2 + (blk >> 7);
  const int hg = (blk >> 3) & 15;

  // ---- persistent weight fragments (bf16): wave owns 16 gate-cols
  short8 Bhh0[10], Bih1[10], Bhh1[10];
  {
    int ncol = wave * 16 + lm;       // local col 0..79 (= 4k+q)
    int k = ncol >> 2, q = ncol & 3;
    int r = q * 320 + hg * 20 + k;   // original gate row
    const float* p0 = w_hh + (size_t)r * 320 + quad * 8;
    const float* p1 = w_hh + (size_t)(1280 + r) * 320 + quad * 8;
    const float* pi = w_ih + (size_t)(1280 + r) * 320 + quad * 8;
#pragma unroll
    for (int kk = 0; kk < 10; ++kk) {
      Bhh0[kk] = loadw8(p0 + kk * 32);
      Bhh1[kk] = loadw8(p1 + kk * 32);
      Bih1[kk] = loadw8(pi + kk * 32);
    }
  }
  const float bias1v = bias1p[hg * 80 + wave * 16 + lm];

  // ---- pointwise mapping
  const int un  = tid / 10;
  const int ukp = tid - un * 10;
  const int n_g = bg * 32 + un;
  const int kc  = hg * 20 + ukp * 2;

  // ---- staging address precompute, 8B granularity
  int smc[8], spc[8];
#pragma unroll
  for (int it = 0; it < 8; ++it) {
    int cid = tid + it * 320;        // 0..2559 = 32 rows x 80 chunks(8B)
    int m = cid / 80;
    int c8 = cid - m * 80;
    int c16 = c8 >> 1, h = c8 & 1;
    int p16 = c16 + m; if (p16 >= 40) p16 -= 40;
    smc[it] = m * 320 + c8 * 4;
    spc[it] = m * 320 + p16 * 8 + h * 4;
  }
  const size_t gbase = (size_t)bg * 32 * 320;

  float c0s0 = c0[(size_t)n_g * 320 + kc];
  float c0s1 = c0[(size_t)n_g * 320 + kc + 1];
  float c1s0 = c0[(size_t)(512 + n_g) * 320 + kc];
  float c1s1 = c0[(size_t)(512 + n_g) * 320 + kc + 1];

  uint32_t* flags0  = flags;
  uint32_t* flags1  = flags + 256 * FLAGSTRIDE;
  uint32_t* myflag0 = flags0 + (size_t)(bg * 16 + hg) * FLAGSTRIDE;
  uint32_t* myflag1 = flags1 + (size_t)(bg * 16 + hg) * FLAGSTRIDE;

  // ---- pre-stage Hl0 <- initial h0 (prep slot 1): ALWAYS slow (IC-fresh)
  {
    const uint16_t* s0b = Hx0 + HSZ + gbase;
    u64t r0[8];
#pragma unroll
    for (int it = 0; it < 8; ++it) r0[it] = slowld64(s0b + smc[it]);
    vm_drain();
#pragma unroll
    for (int it = 0; it < 8; ++it) *(u64t*)(Hl0 + spc[it]) = r0[it];
    __syncthreads();
  }

  // ---- prefetch x/G0p row for tick 0
  float4 gxa, gxb;
  {
    const int v = x[n_g];
    const float* gx = G0p + (size_t)v * 1280 + hg * 80 + ukp * 8;
    gxa = ((const float4*)gx)[0];
    gxb = ((const float4*)gx)[1];
  }

#pragma unroll 1
  for (int t = 0; t <= USTEPS; ++t) {
    const bool do0 = (t < USTEPS);   // layer0 computes h0[t]
    const bool do1 = (t >= 1);       // layer1 computes h1[t-1]

    // ---- phase A (Hl0 = h0[t-1]): gates0 = Hl0@Bhh0 ; gates1 += Hl0@Bih1
    f32x4 ag00 = {0.f, 0.f, 0.f, 0.f}, ag01 = {0.f, 0.f, 0.f, 0.f};
    f32x4 ag10 = {bias1v, bias1v, bias1v, bias1v}, ag11 = ag10;
#pragma unroll
    for (int kk = 0; kk < 10; ++kk) {
      int cch = kk * 4 + quad;
      int p0a = cch + lm;      if (p0a >= 40) p0a -= 40;
      int p1a = cch + lm + 16; if (p1a >= 40) p1a -= 40;
      short8 a00 = *(const short8*)(Hl0 + lm * 320 + p0a * 8);
      short8 a01 = *(const short8*)(Hl0 + (lm + 16) * 320 + p1a * 8);
      if (do0) {
        ag00 = __builtin_amdgcn_mfma_f32_16x16x32_bf16(a00, Bhh0[kk], ag00, 0, 0, 0);
        ag01 = __builtin_amdgcn_mfma_f32_16x16x32_bf16(a01, Bhh0[kk], ag01, 0, 0, 0);
      }
      if (do1) {
        ag10 = __builtin_amdgcn_mfma_f32_16x16x32_bf16(a00, Bih1[kk], ag10, 0, 0, 0);
        ag11 = __builtin_amdgcn_mfma_f32_16x16x32_bf16(a01, Bih1[kk], ag11, 0, 0, 0);
      }
    }

    // ---- poll1: h1[t-2] exchange complete. flag1=t was published during
    //      tick t-1's pw1 -> ~a full tick old -> first read satisfies.
    if (do1 && t >= 2 && tid < 16) {
      uint32_t* peer = flags1 + (size_t)(bg * 16 + tid) * FLAGSTRIDE;
      while (__hip_atomic_load(peer, __ATOMIC_RELAXED,
                               __HIP_MEMORY_SCOPE_AGENT) < (uint32_t)t) {
      }
    }
    __syncthreads();                                   // B0

    // ---- issue Hl1 staging loads; cover part of the RT with the gates0
    //      LDS writes (independent); then drain + land Hl1. (R8-proven
    //      pattern: asm loads live across non-vmem code, drained later.)
    u64t r1[8];
    if (do1) {
      const uint16_t* s1b = Hx1 + (size_t)(t & 1) * HSZ + gbase;
      if (FAST && t == 1) {
#pragma unroll
        for (int it = 0; it < 8; ++it) r1[it] = slowld64(s1b + smc[it]);
      } else {
#pragma unroll
        for (int it = 0; it < 8; ++it) r1[it] = exld64<FAST>(s1b + smc[it]);
      }
    }
    if (do0) {
#pragma unroll
      for (int r = 0; r < 4; ++r) {
        gates0[(quad * 4 + r) * GSTRIDE + wave * 16 + lm]      = ag00[r];
        gates0[(16 + quad * 4 + r) * GSTRIDE + wave * 16 + lm] = ag01[r];
      }
    }
    if (do1) {
      vm_drain();
#pragma unroll
      for (int it = 0; it < 8; ++it) *(u64t*)(Hl1 + spc[it]) = r1[it];
    }
    __syncthreads();                                   // B1

    // ---- layer 0 pointwise -> h0[t] -> Hx0 (sc0 one-shot store)
    if (do0) {
      const float* gp = gates0 + un * GSTRIDE + ukp * 8;
      float i0 = gp[0] + gxa.x, f0 = gp[1] + gxa.y, g0 = gp[2] + gxa.z, o0 = gp[3] + gxa.w;
      float i1 = gp[4] + gxb.x, f1 = gp[5] + gxb.y, g1 = gp[6] + gxb.z, o1 = gp[7] + gxb.w;
      c0s0 = sigm(f0) * c0s0 + sigm(i0) * tanh_(g0);
      c0s1 = sigm(f1) * c0s1 + sigm(i1) * tanh_(g1);
      float ha = sigm(o0) * tanh_(c0s0);
      float hb = sigm(o1) * tanh_(c0s1);
      uint32_t packed = (uint32_t)f2bf(ha) | ((uint32_t)f2bf(hb) << 16);
      exst32<FAST>(Hx0 + (size_t)(t & 1) * HSZ + (size_t)n_g * 320 + kc, packed);
      if (t == USTEPS - 1) {
        *(float2*)(out + HGOFF + (size_t)n_g * 320 + kc) = make_float2(ha, hb);
        *(float2*)(out + CGOFF + (size_t)n_g * 320 + kc) = make_float2(c0s0, c0s1);
      }
    }

    // ---- phase B: gates1 += Hl1@Bhh1 (covers the Hx0 store ack)
    if (do1) {
#pragma unroll
      for (int kk = 0; kk < 10; ++kk) {
        int cch = kk * 4 + quad;
        int p0a = cch + lm;      if (p0a >= 40) p0a -= 40;
        int p1a = cch + lm + 16; if (p1a >= 40) p1a -= 40;
        short8 a10 = *(const short8*)(Hl1 + lm * 320 + p0a * 8);
        short8 a11 = *(const short8*)(Hl1 + (lm + 16) * 320 + p1a * 8);
        ag10 = __builtin_amdgcn_mfma_f32_16x16x32_bf16(a10, Bhh1[kk], ag10, 0, 0, 0);
        ag11 = __builtin_amdgcn_mfma_f32_16x16x32_bf16(a11, Bhh1[kk], ag11, 0, 0, 0);
      }
    }

    // ---- publish flag0: drain (ack arrived under phase B) + LDS counter;
    //      gap to poll0 = B2 + pw1 + prefetch ~ 1 RT.
    if (do0) {
      vm_drain();
      if (lane == 0) {
        int old = atomicAdd(ctr0, 1);
        if ((old % 5) == 4)
          __hip_atomic_store(myflag0, (uint32_t)(t + 1), __ATOMIC_RELAXED,
                             __HIP_MEMORY_SCOPE_AGENT);
      }
    }

    if (do1) {
#pragma unroll
      for (int r = 0; r < 4; ++r) {
        gates1[(quad * 4 + r) * GSTRIDE + wave * 16 + lm]      = ag10[r];
        gates1[(16 + quad * 4 + r) * GSTRIDE + wave * 16 + lm] = ag11[r];
      }
    }
    __syncthreads();                                   // B2

    // ---- layer 1 pointwise: Hx1 store -> drain -> flag1 publish -> g out
    //      (flag1 is then ~a full tick ahead of its poll next tick)
    if (do1) {
      const int u1 = t - 1;
      const float* gp = gates1 + un * GSTRIDE + ukp * 8;
      float i0 = gp[0], f0 = gp[1], g0 = gp[2], o0 = gp[3];
      float i1 = gp[4], f1 = gp[5], g1 = gp[6], o1 = gp[7];
      c1s0 = sigm(f0) * c1s0 + sigm(i0) * tanh_(g0);
      c1s1 = sigm(f1) * c1s1 + sigm(i1) * tanh_(g1);
      float ha = sigm(o0) * tanh_(c1s0);
      float hb = sigm(o1) * tanh_(c1s1);
      uint32_t packed = (uint32_t)f2bf(ha) | ((uint32_t)f2bf(hb) << 16);
      exst32<FAST>(Hx1 + (size_t)((t + 1) & 1) * HSZ + (size_t)n_g * 320 + kc, packed);
      vm_drain();
      if (lane == 0) {
        int old = atomicAdd(ctr1, 1);
        if ((old % 5) == 4)
          __hip_atomic_store(myflag1, (uint32_t)(t + 1), __ATOMIC_RELAXED,
                             __HIP_MEMORY_SCOPE_AGENT);
      }
      *(float2*)(out + (size_t)u1 * GSTEP + (size_t)n_g * 320 + kc) = make_float2(ha, hb);
      if (t == USTEPS) {
        *(float2*)(out + HGOFF + (size_t)(512 + n_g) * 320 + kc) = make_float2(ha, hb);
        *(float2*)(out + CGOFF + (size_t)(512 + n_g) * 320 + kc) = make_float2(c1s0, c1s1);
      }
    }

    // ---- prefetch next tick's x/G0p row
    if (t + 1 < USTEPS) {
      const int v = x[(t + 1) * 512 + n_g];
      const float* gx = G0p + (size_t)v * 1280 + hg * 80 + ukp * 8;
      gxa = ((const float4*)gx)[0];
      gxb = ((const float4*)gx)[1];
    }

    // ---- tick end: poll0 -> stage Hl0 <- h0[t]
    if (t < USTEPS) {
      if (tid < 16) {
        uint32_t* peer = flags0 + (size_t)(bg * 16 + tid) * FLAGSTRIDE;
        while (__hip_atomic_load(peer, __ATOMIC_RELAXED,
                                 __HIP_MEMORY_SCOPE_AGENT) < (uint32_t)(t + 1)) {
        }
      }
      __syncthreads();                                 // B3
      const uint16_t* s0b = Hx0 + (size_t)(t & 1) * HSZ + gbase;
      u64t r0[8];
#pragma unroll
      for (int it = 0; it < 8; ++it) r0[it] = exld64<FAST>(s0b + smc[it]);
      vm_drain();
#pragma unroll
      for (int it = 0; it < 8; ++it) *(u64t*)(Hl0 + spc[it]) = r0[it];
      __syncthreads();                                 // B4
    }
  }
}

// ---------------------------------------------------------------------------
// main persistent kernel: fail-safe XCD handshake (R13 verbatim), scoped loop
// ---------------------------------------------------------------------------
__global__ void __launch_bounds__(320, 2)
rnnt_kernel(const int* __restrict__ x,
            const float* __restrict__ c0,
            const float* __restrict__ w_ih,
            const float* __restrict__ w_hh,
            const float* __restrict__ G0p,
            const float* __restrict__ bias1p,
            uint16_t* __restrict__ Hx0,
            uint16_t* __restrict__ Hx1,
            uint32_t* __restrict__ flags,
            float* __restrict__ out) {
  __shared__ __align__(16) uint16_t Hl0[32 * 320];
  __shared__ __align__(16) uint16_t Hl1[32 * 320];
  __shared__ __align__(16) float    gates0[32 * GSTRIDE];
  __shared__ __align__(16) float    gates1[32 * GSTRIDE];
  __shared__ int ctr0, ctr1;
  __shared__ uint32_t v0sh;

  const int tid = threadIdx.x;
  const int blk = blockIdx.x;
  const int bg = (blk & 7) * 2 + (blk >> 7);
  const int hg = (blk >> 3) & 15;

  // XCC probe: hwreg(id=20, offset=0, size=4) = 20 | (3<<11). Garbage or
  // per-CU-varying reads force the slow path via the checks below (safe).
  const uint32_t xcc = (uint32_t)__builtin_amdgcn_s_getreg((3 << 11) | 20) & 0xffu;
  const uint32_t mine = 0x100u | xcc;
  uint32_t* xcdtab = flags + 8192;

  if (tid == 0) {
    ctr0 = 0; ctr1 = 0;
    __hip_atomic_store(&xcdtab[bg * 16 + hg], mine, __ATOMIC_RELAXED,
                       __HIP_MEMORY_SCOPE_AGENT);
  }
  uint32_t v = 0;
  if (tid < 256) {
    do {
      v = __hip_atomic_load(&xcdtab[tid], __ATOMIC_RELAXED,
                            __HIP_MEMORY_SCOPE_AGENT);
    } while (v == 0u);
    if (tid == 0) v0sh = v;
  }
  __syncthreads();
  const uint32_t v0 = v0sh;
  const int anydiff = __syncthreads_or((tid < 256) ? (int)(v != v0) : 0);
  const int anybad  = __syncthreads_or(
      (tid < 256 && (tid >> 4) == bg) ? (int)(v != mine) : 0);
  const bool fastok = (anydiff != 0) && (anybad == 0);

  if (fastok)
    run_loop<true>(x, c0, w_ih, w_hh, G0p, bias1p, Hx0, Hx1, flags, out,
                   Hl0, Hl1, gates0, gates1, &ctr0, &ctr1);
  else
    run_loop<false>(x, c0, w_ih, w_hh, G0p, bias1p, Hx0, Hx1, flags, out,
                    Hl0, Hl1, gates0, gates1, &ctr0, &ctr1);
}

extern "C" void kernel_launch(void* const* d_in, const int* in_sizes, int n_in,
                              void* d_out, int out_size, void* d_ws, size_t ws_size,
                              hipStream_t stream) {
  (void)in_sizes; (void)n_in; (void)out_size; (void)ws_size;
  const int*   x     = (const int*)d_in[0];
  const float* h0    = (const float*)d_in[1];
  const float* c0    = (const float*)d_in[2];
  const float* embed = (const float*)d_in[3];
  const float* w_ih  = (const float*)d_in[4];
  const float* w_hh  = (const float*)d_in[5];
  const float* b_ih  = (const float*)d_in[6];
  const float* b_hh  = (const float*)d_in[7];
  float* out = (float*)d_out;

  char* ws = (char*)d_ws;
  float*    G0p   = (float*)(ws);              // 29*1280*4   = 148480 B
  float*    b1p   = (float*)(ws + 148480);     // 1280*4      =   5120 B
  uint32_t* flags = (uint32_t*)(ws + 153600);  // 8448*4      =  33792 B
  uint16_t* Hx0   = (uint16_t*)(ws + 187392);  // 2*512*320*2 = 655360 B
  uint16_t* Hx1   = (uint16_t*)(ws + 842752);  // 2*512*320*2 = 655360 B

  hipLaunchKernelGGL(prep_kernel, dim3((PREP_HI + 255) / 256), dim3(256), 0,
                     stream, embed, w_ih, b_ih, b_hh, h0, G0p, b1p, flags,
                     Hx0, Hx1);

  void* args[] = { (void*)&x, (void*)&c0, (void*)&w_ih, (void*)&w_hh,
                   (void*)&G0p, (void*)&b1p, (void*)&Hx0, (void*)&Hx1,
                   (void*)&flags, (void*)&out };
  hipLaunchCooperativeKernel((const void*)rnnt_kernel, dim3(256), dim3(320),
                             args, 0, stream);
}

// Round 12
// 697.913 us; speedup vs baseline: 1.1020x; 1.0313x over previous
//
#include <hip/hip_runtime.h>
#include <stdint.h>

// RNN-T prediction network: embed lookup + 2-layer LSTM, U=128, N=512, C=320.
// FP32 in/out; internal GEMMs bf16 MFMA + fp32 accumulate.
// Persistent cooperative kernel, 256 WGs = 16 batch-groups x 16 hidden-groups.
// R16: R13 (best, 602us) + ONLY the B0-B1 load-issue reorder (isolated from
//      R15's pitch-85 regression; pitch back to 84):
//        issue Hl1 staging loads -> write gates0 to LDS (covers part of the
//        ~800cy load RT) -> drain -> land Hl1. Pattern ran correctly in R15.
//      R15 lesson: pitch 85 RAISED bank conflicts 2.88e7->4.14e7 and cost
//      15us; the Hl rotation swizzle is already bank-optimal.
//      Proven invariants: grid=256 (512 never launches), sc0 one-shot data
//      at XCD L2 (runtime-gated fail-safe), flags agent-scope IC only
//      (sc0 spin-polls hang), R8 32-row geometry verbatim.

typedef short short8 __attribute__((ext_vector_type(8)));
typedef float f32x4 __attribute__((ext_vector_type(4)));
typedef unsigned long long u64t;

#define USTEPS 128
#define HSZ    (512*320)
#define GSTEP  (512*320)
#define HGOFF  (128*512*320)
#define CGOFF  (HGOFF + 2*512*320)
#define FLAGSTRIDE 16   // uint32s = 64B per slot

__device__ __forceinline__ uint16_t f2bf(float f) {
  union { float f; uint32_t i; } v; v.f = f;
  uint32_t i = v.i;
  return (uint16_t)((i + 0x7fffu + ((i >> 16) & 1u)) >> 16);
}
__device__ __forceinline__ float rcp_(float x) { return __builtin_amdgcn_rcpf(x); }
__device__ __forceinline__ float sigm(float x) { return rcp_(1.0f + __expf(-x)); }
__device__ __forceinline__ float tanh_(float x) {
  float ax = fabsf(x);
  float e  = __expf(-2.0f * ax);
  float t  = (1.0f - e) * rcp_(1.0f + e);
  return x < 0.0f ? -t : t;
}
__device__ __forceinline__ uint4 cvt8(const float* s) {
  float4 a = ((const float4*)s)[0];
  float4 b = ((const float4*)s)[1];
  uint4 r;
  r.x = (uint32_t)f2bf(a.x) | ((uint32_t)f2bf(a.y) << 16);
  r.y = (uint32_t)f2bf(a.z) | ((uint32_t)f2bf(a.w) << 16);
  r.z = (uint32_t)f2bf(b.x) | ((uint32_t)f2bf(b.y) << 16);
  r.w = (uint32_t)f2bf(b.z) | ((uint32_t)f2bf(b.w) << 16);
  return r;
}
__device__ __forceinline__ short8 loadw8(const float* p) {
  float4 a = ((const float4*)p)[0];
  float4 b = ((const float4*)p)[1];
  short8 r;
  r[0] = (short)f2bf(a.x); r[1] = (short)f2bf(a.y);
  r[2] = (short)f2bf(a.z); r[3] = (short)f2bf(a.w);
  r[4] = (short)f2bf(b.x); r[5] = (short)f2bf(b.y);
  r[6] = (short)f2bf(b.z); r[7] = (short)f2bf(b.w);
  return r;
}

// ---- scope-selectable one-shot data-exchange ops (R8-proven) --------------
__device__ __forceinline__ u64t slowld64(const void* p) {
  return __hip_atomic_load((const u64t*)p, __ATOMIC_RELAXED,
                           __HIP_MEMORY_SCOPE_AGENT);
}
template<bool FAST>
__device__ __forceinline__ u64t exld64(const void* p) {
  if (FAST) {
    u64t r;
    asm volatile("global_load_dwordx2 %0, %1, off sc0" : "=v"(r) : "v"(p));
    return r;
  } else {
    return slowld64(p);
  }
}
template<bool FAST>
__device__ __forceinline__ void exst32(void* p, uint32_t v) {
  if (FAST) {
    asm volatile("global_store_dword %0, %1, off sc0" :: "v"(p), "v"(v) : "memory");
  } else {
    __hip_atomic_store((uint32_t*)p, v, __ATOMIC_RELAXED,
                       __HIP_MEMORY_SCOPE_AGENT);
  }
}
__device__ __forceinline__ void vm_drain() {
  asm volatile("s_waitcnt vmcnt(0)" ::: "memory");
}

// ---------------------------------------------------------------------------
// prep: G0p table, bias1p, flag+xcdtab zeroing, h0 -> bf16 prefill of
// exchange slot 1 for both layers. (R13 verbatim)
// ---------------------------------------------------------------------------
#define PREP_G0   (29 * 1280)
#define PREP_B1   (PREP_G0 + 1280)
#define PREP_FL   (PREP_B1 + 8448)          // 2*4096 flags + 256 xcdtab
#define PREP_HI   (PREP_FL + 2 * 512 * 40)  // 40960 cvt8 items
__global__ void prep_kernel(const float* __restrict__ embed,
                            const float* __restrict__ w_ih,
                            const float* __restrict__ b_ih,
                            const float* __restrict__ b_hh,
                            const float* __restrict__ h0,
                            float* __restrict__ G0p,
                            float* __restrict__ bias1p,
                            uint32_t* __restrict__ flags,
                            uint16_t* __restrict__ Hx0,
                            uint16_t* __restrict__ Hx1) {
  int tid = blockIdx.x * blockDim.x + threadIdx.x;
  if (tid < PREP_G0) {
    int v = tid / 1280, col = tid % 1280;
    int hg = col / 80, idx = col % 80;
    int k = idx >> 2, q = idx & 3;
    int r = q * 320 + hg * 20 + k;
    float acc = b_ih[r] + b_hh[r];
    if (v < 28) {
      const float4* e = (const float4*)(embed + (size_t)v * 320);
      const float4* w = (const float4*)(w_ih + (size_t)r * 320);
#pragma unroll 4
      for (int i = 0; i < 80; ++i) {
        float4 a = e[i], b = w[i];
        acc += a.x * b.x + a.y * b.y + a.z * b.z + a.w * b.w;
      }
    }
    G0p[tid] = acc;
  } else if (tid < PREP_B1) {
    int col = tid - PREP_G0;
    int hg = col / 80, idx = col % 80;
    int k = idx >> 2, q = idx & 3;
    int r = q * 320 + hg * 20 + k;
    bias1p[col] = b_ih[1280 + r] + b_hh[1280 + r];
  } else if (tid < PREP_FL) {
    flags[tid - PREP_B1] = 0;
  } else if (tid < PREP_HI) {
    int id = tid - PREP_FL;              // 0..40959, 8 elements each
    int layer = id / 20480;
    int rem = id - layer * 20480;        // n*40 + c
    int n = rem / 40, c = rem - n * 40;
    const float* src = h0 + (size_t)layer * HSZ + (size_t)n * 320 + c * 8;
    uint16_t* dst = (layer ? Hx1 : Hx0) + HSZ + (size_t)n * 320 + c * 8;
    *(uint4*)dst = cvt8(src);
  }
}

// ---------------------------------------------------------------------------
// main loop body, templated on data-exchange scope (flags always agent/IC)
// ---------------------------------------------------------------------------
template<bool FAST>
__device__ __forceinline__ void run_loop(
    const int* __restrict__ x, const float* __restrict__ c0,
    const float* __restrict__ w_ih, const float* __restrict__ w_hh,
    const float* __restrict__ G0p, const float* __restrict__ bias1p,
    uint16_t* __restrict__ Hx0, uint16_t* __restrict__ Hx1,
    uint32_t* __restrict__ flags, float* __restrict__ out,
    uint16_t* Hl0, uint16_t* Hl1, float* gates0, float* gates1,
    int* ctr0, int* ctr1) {
  const int tid  = threadIdx.x;
  const int wave = tid >> 6;
  const int lane = tid & 63;
  const int quad = lane >> 4;
  const int lm   = lane & 15;
  const int blk  = blockIdx.x;
  const int bg = (blk & 7) * 2 + (blk >> 7);
  const int hg = (blk >> 3) & 15;

  // ---- persistent weight fragments (bf16): wave owns 16 gate-cols
  short8 Bhh0[10], Bih1[10], Bhh1[10];
  {
    int ncol = wave * 16 + lm;       // local col 0..79 (= 4k+q)
    int k = ncol >> 2, q = ncol & 3;
    int r = q * 320 + hg * 20 + k;   // original gate row
    const float* p0 = w_hh + (size_t)r * 320 + quad * 8;
    const float* p1 = w_hh + (size_t)(1280 + r) * 320 + quad * 8;
    const float* pi = w_ih + (size_t)(1280 + r) * 320 + quad * 8;
#pragma unroll
    for (int kk = 0; kk < 10; ++kk) {
      Bhh0[kk] = loadw8(p0 + kk * 32);
      Bhh1[kk] = loadw8(p1 + kk * 32);
      Bih1[kk] = loadw8(pi + kk * 32);
    }
  }
  const float bias1v = bias1p[hg * 80 + wave * 16 + lm];

  // ---- pointwise mapping
  const int un  = tid / 10;
  const int ukp = tid - un * 10;
  const int n_g = bg * 32 + un;
  const int kc  = hg * 20 + ukp * 2;

  // ---- staging address precompute, 8B granularity
  int smc[8], spc[8];
#pragma unroll
  for (int it = 0; it < 8; ++it) {
    int cid = tid + it * 320;        // 0..2559 = 32 rows x 80 chunks(8B)
    int m = cid / 80;
    int c8 = cid - m * 80;
    int c16 = c8 >> 1, h = c8 & 1;
    int p16 = c16 + m; if (p16 >= 40) p16 -= 40;
    smc[it] = m * 320 + c8 * 4;
    spc[it] = m * 320 + p16 * 8 + h * 4;
  }
  const size_t gbase = (size_t)bg * 32 * 320;

  float c0s0 = c0[(size_t)n_g * 320 + kc];
  float c0s1 = c0[(size_t)n_g * 320 + kc + 1];
  float c1s0 = c0[(size_t)(512 + n_g) * 320 + kc];
  float c1s1 = c0[(size_t)(512 + n_g) * 320 + kc + 1];

  uint32_t* flags0  = flags;
  uint32_t* flags1  = flags + 256 * FLAGSTRIDE;
  uint32_t* myflag0 = flags0 + (size_t)(bg * 16 + hg) * FLAGSTRIDE;
  uint32_t* myflag1 = flags1 + (size_t)(bg * 16 + hg) * FLAGSTRIDE;

  // ---- pre-stage Hl0 <- initial h0 (prep slot 1): ALWAYS slow (IC-fresh)
  {
    const uint16_t* s0b = Hx0 + HSZ + gbase;
    u64t r0[8];
#pragma unroll
    for (int it = 0; it < 8; ++it) r0[it] = slowld64(s0b + smc[it]);
    vm_drain();
#pragma unroll
    for (int it = 0; it < 8; ++it) *(u64t*)(Hl0 + spc[it]) = r0[it];
    __syncthreads();
  }

  // ---- prefetch x/G0p row for tick 0
  float4 gxa, gxb;
  {
    const int v = x[n_g];
    const float* gx = G0p + (size_t)v * 1280 + hg * 80 + ukp * 8;
    gxa = ((const float4*)gx)[0];
    gxb = ((const float4*)gx)[1];
  }

#pragma unroll 1
  for (int t = 0; t <= USTEPS; ++t) {
    const bool do0 = (t < USTEPS);   // layer0 computes h0[t]
    const bool do1 = (t >= 1);       // layer1 computes h1[t-1]

    // ---- phase A (Hl0 = h0[t-1]): gates0 = Hl0@Bhh0 ; gates1 += Hl0@Bih1
    f32x4 ag00 = {0.f, 0.f, 0.f, 0.f}, ag01 = {0.f, 0.f, 0.f, 0.f};
    f32x4 ag10 = {bias1v, bias1v, bias1v, bias1v}, ag11 = ag10;
#pragma unroll
    for (int kk = 0; kk < 10; ++kk) {
      int cch = kk * 4 + quad;
      int p0a = cch + lm;      if (p0a >= 40) p0a -= 40;
      int p1a = cch + lm + 16; if (p1a >= 40) p1a -= 40;
      short8 a00 = *(const short8*)(Hl0 + lm * 320 + p0a * 8);
      short8 a01 = *(const short8*)(Hl0 + (lm + 16) * 320 + p1a * 8);
      if (do0) {
        ag00 = __builtin_amdgcn_mfma_f32_16x16x32_bf16(a00, Bhh0[kk], ag00, 0, 0, 0);
        ag01 = __builtin_amdgcn_mfma_f32_16x16x32_bf16(a01, Bhh0[kk], ag01, 0, 0, 0);
      }
      if (do1) {
        ag10 = __builtin_amdgcn_mfma_f32_16x16x32_bf16(a00, Bih1[kk], ag10, 0, 0, 0);
        ag11 = __builtin_amdgcn_mfma_f32_16x16x32_bf16(a01, Bih1[kk], ag11, 0, 0, 0);
      }
    }

    // ---- poll1: h1[t-2] exchange complete. flag1=t was published during
    //      tick t-1's pw1 -> ~a full tick old -> first read satisfies.
    if (do1 && t >= 2 && tid < 16) {
      uint32_t* peer = flags1 + (size_t)(bg * 16 + tid) * FLAGSTRIDE;
      while (__hip_atomic_load(peer, __ATOMIC_RELAXED,
                               __HIP_MEMORY_SCOPE_AGENT) < (uint32_t)t) {
      }
    }
    __syncthreads();                                   // B0

    // ---- issue Hl1 staging loads; cover part of the RT with the gates0
    //      LDS writes (independent); then drain + land Hl1.
    u64t r1[8];
    if (do1) {
      const uint16_t* s1b = Hx1 + (size_t)(t & 1) * HSZ + gbase;
      if (FAST && t == 1) {
#pragma unroll
        for (int it = 0; it < 8; ++it) r1[it] = slowld64(s1b + smc[it]);
      } else {
#pragma unroll
        for (int it = 0; it < 8; ++it) r1[it] = exld64<FAST>(s1b + smc[it]);
      }
    }
    if (do0) {
#pragma unroll
      for (int r = 0; r < 4; ++r) {
        gates0[(quad * 4 + r) * 84 + wave * 16 + lm]      = ag00[r];
        gates0[(16 + quad * 4 + r) * 84 + wave * 16 + lm] = ag01[r];
      }
    }
    if (do1) {
      vm_drain();
#pragma unroll
      for (int it = 0; it < 8; ++it) *(u64t*)(Hl1 + spc[it]) = r1[it];
    }
    __syncthreads();                                   // B1

    // ---- layer 0 pointwise -> h0[t] -> Hx0 (sc0 one-shot store)
    if (do0) {
      const float* gp = gates0 + un * 84 + ukp * 8;
      float i0 = gp[0] + gxa.x, f0 = gp[1] + gxa.y, g0 = gp[2] + gxa.z, o0 = gp[3] + gxa.w;
      float i1 = gp[4] + gxb.x, f1 = gp[5] + gxb.y, g1 = gp[6] + gxb.z, o1 = gp[7] + gxb.w;
      c0s0 = sigm(f0) * c0s0 + sigm(i0) * tanh_(g0);
      c0s1 = sigm(f1) * c0s1 + sigm(i1) * tanh_(g1);
      float ha = sigm(o0) * tanh_(c0s0);
      float hb = sigm(o1) * tanh_(c0s1);
      uint32_t packed = (uint32_t)f2bf(ha) | ((uint32_t)f2bf(hb) << 16);
      exst32<FAST>(Hx0 + (size_t)(t & 1) * HSZ + (size_t)n_g * 320 + kc, packed);
      if (t == USTEPS - 1) {
        *(float2*)(out + HGOFF + (size_t)n_g * 320 + kc) = make_float2(ha, hb);
        *(float2*)(out + CGOFF + (size_t)n_g * 320 + kc) = make_float2(c0s0, c0s1);
      }
    }

    // ---- phase B: gates1 += Hl1@Bhh1 (covers the Hx0 store ack)
    if (do1) {
#pragma unroll
      for (int kk = 0; kk < 10; ++kk) {
        int cch = kk * 4 + quad;
        int p0a = cch + lm;      if (p0a >= 40) p0a -= 40;
        int p1a = cch + lm + 16; if (p1a >= 40) p1a -= 40;
        short8 a10 = *(const short8*)(Hl1 + lm * 320 + p0a * 8);
        short8 a11 = *(const short8*)(Hl1 + (lm + 16) * 320 + p1a * 8);
        ag10 = __builtin_amdgcn_mfma_f32_16x16x32_bf16(a10, Bhh1[kk], ag10, 0, 0, 0);
        ag11 = __builtin_amdgcn_mfma_f32_16x16x32_bf16(a11, Bhh1[kk], ag11, 0, 0, 0);
      }
    }

    // ---- publish flag0: drain (ack arrived under phase B) + LDS counter;
    //      gap to poll0 = B2 + pw1 + prefetch ~ 1 RT.
    if (do0) {
      vm_drain();
      if (lane == 0) {
        int old = atomicAdd(ctr0, 1);
        if ((old % 5) == 4)
          __hip_atomic_store(myflag0, (uint32_t)(t + 1), __ATOMIC_RELAXED,
                             __HIP_MEMORY_SCOPE_AGENT);
      }
    }

    if (do1) {
#pragma unroll
      for (int r = 0; r < 4; ++r) {
        gates1[(quad * 4 + r) * 84 + wave * 16 + lm]      = ag10[r];
        gates1[(16 + quad * 4 + r) * 84 + wave * 16 + lm] = ag11[r];
      }
    }
    __syncthreads();                                   // B2

    // ---- layer 1 pointwise: Hx1 store -> drain -> flag1 publish -> g out
    //      (flag1 is then ~a full tick ahead of its poll next tick)
    if (do1) {
      const int u1 = t - 1;
      const float* gp = gates1 + un * 84 + ukp * 8;
      float i0 = gp[0], f0 = gp[1], g0 = gp[2], o0 = gp[3];
      float i1 = gp[4], f1 = gp[5], g1 = gp[6], o1 = gp[7];
      c1s0 = sigm(f0) * c1s0 + sigm(i0) * tanh_(g0);
      c1s1 = sigm(f1) * c1s1 + sigm(i1) * tanh_(g1);
      float ha = sigm(o0) * tanh_(c1s0);
      float hb = sigm(o1) * tanh_(c1s1);
      uint32_t packed = (uint32_t)f2bf(ha) | ((uint32_t)f2bf(hb) << 16);
      exst32<FAST>(Hx1 + (size_t)((t + 1) & 1) * HSZ + (size_t)n_g * 320 + kc, packed);
      vm_drain();
      if (lane == 0) {
        int old = atomicAdd(ctr1, 1);
        if ((old % 5) == 4)
          __hip_atomic_store(myflag1, (uint32_t)(t + 1), __ATOMIC_RELAXED,
                             __HIP_MEMORY_SCOPE_AGENT);
      }
      *(float2*)(out + (size_t)u1 * GSTEP + (size_t)n_g * 320 + kc) = make_float2(ha, hb);
      if (t == USTEPS) {
        *(float2*)(out + HGOFF + (size_t)(512 + n_g) * 320 + kc) = make_float2(ha, hb);
        *(float2*)(out + CGOFF + (size_t)(512 + n_g) * 320 + kc) = make_float2(c1s0, c1s1);
      }
    }

    // ---- prefetch next tick's x/G0p row
    if (t + 1 < USTEPS) {
      const int v = x[(t + 1) * 512 + n_g];
      const float* gx = G0p + (size_t)v * 1280 + hg * 80 + ukp * 8;
      gxa = ((const float4*)gx)[0];
      gxb = ((const float4*)gx)[1];
    }

    // ---- tick end: poll0 -> stage Hl0 <- h0[t]
    if (t < USTEPS) {
      if (tid < 16) {
        uint32_t* peer = flags0 + (size_t)(bg * 16 + tid) * FLAGSTRIDE;
        while (__hip_atomic_load(peer, __ATOMIC_RELAXED,
                                 __HIP_MEMORY_SCOPE_AGENT) < (uint32_t)(t + 1)) {
        }
      }
      __syncthreads();                                 // B3
      const uint16_t* s0b = Hx0 + (size_t)(t & 1) * HSZ + gbase;
      u64t r0[8];
#pragma unroll
      for (int it = 0; it < 8; ++it) r0[it] = exld64<FAST>(s0b + smc[it]);
      vm_drain();
#pragma unroll
      for (int it = 0; it < 8; ++it) *(u64t*)(Hl0 + spc[it]) = r0[it];
      __syncthreads();                                 // B4
    }
  }
}

// ---------------------------------------------------------------------------
// main persistent kernel: fail-safe XCD handshake (R13 verbatim), scoped loop
// ---------------------------------------------------------------------------
__global__ void __launch_bounds__(320, 2)
rnnt_kernel(const int* __restrict__ x,
            const float* __restrict__ c0,
            const float* __restrict__ w_ih,
            const float* __restrict__ w_hh,
            const float* __restrict__ G0p,
            const float* __restrict__ bias1p,
            uint16_t* __restrict__ Hx0,
            uint16_t* __restrict__ Hx1,
            uint32_t* __restrict__ flags,
            float* __restrict__ out) {
  __shared__ __align__(16) uint16_t Hl0[32 * 320];
  __shared__ __align__(16) uint16_t Hl1[32 * 320];
  __shared__ __align__(16) float    gates0[32 * 84];
  __shared__ __align__(16) float    gates1[32 * 84];
  __shared__ int ctr0, ctr1;
  __shared__ uint32_t v0sh;

  const int tid = threadIdx.x;
  const int blk = blockIdx.x;
  const int bg = (blk & 7) * 2 + (blk >> 7);
  const int hg = (blk >> 3) & 15;

  // XCC probe: hwreg(id=20, offset=0, size=4) = 20 | (3<<11). Garbage or
  // per-CU-varying reads force the slow path via the checks below (safe).
  const uint32_t xcc = (uint32_t)__builtin_amdgcn_s_getreg((3 << 11) | 20) & 0xffu;
  const uint32_t mine = 0x100u | xcc;
  uint32_t* xcdtab = flags + 8192;

  if (tid == 0) {
    ctr0 = 0; ctr1 = 0;
    __hip_atomic_store(&xcdtab[bg * 16 + hg], mine, __ATOMIC_RELAXED,
                       __HIP_MEMORY_SCOPE_AGENT);
  }
  uint32_t v = 0;
  if (tid < 256) {
    do {
      v = __hip_atomic_load(&xcdtab[tid], __ATOMIC_RELAXED,
                            __HIP_MEMORY_SCOPE_AGENT);
    } while (v == 0u);
    if (tid == 0) v0sh = v;
  }
  __syncthreads();
  const uint32_t v0 = v0sh;
  const int anydiff = __syncthreads_or((tid < 256) ? (int)(v != v0) : 0);
  const int anybad  = __syncthreads_or(
      (tid < 256 && (tid >> 4) == bg) ? (int)(v != mine) : 0);
  const bool fastok = (anydiff != 0) && (anybad == 0);

  if (fastok)
    run_loop<true>(x, c0, w_ih, w_hh, G0p, bias1p, Hx0, Hx1, flags, out,
                   Hl0, Hl1, gates0, gates1, &ctr0, &ctr1);
  else
    run_loop<false>(x, c0, w_ih, w_hh, G0p, bias1p, Hx0, Hx1, flags, out,
                    Hl0, Hl1, gates0, gates1, &ctr0, &ctr1);
}

extern "C" void kernel_launch(void* const* d_in, const int* in_sizes, int n_in,
                              void* d_out, int out_size, void* d_ws, size_t ws_size,
                              hipStream_t stream) {
  (void)in_sizes; (void)n_in; (void)out_size; (void)ws_size;
  const int*   x     = (const int*)d_in[0];
  const float* h0    = (const float*)d_in[1];
  const float* c0    = (const float*)d_in[2];
  const float* embed = (const float*)d_in[3];
  const float* w_ih  = (const float*)d_in[4];
  const float* w_hh  = (const float*)d_in[5];
  const float* b_ih  = (const float*)d_in[6];
  const float* b_hh  = (const float*)d_in[7];
  float* out = (float*)d_out;

  char* ws = (char*)d_ws;
  float*    G0p   = (float*)(ws);              // 29*1280*4   = 148480 B
  float*    b1p   = (float*)(ws + 148480);     // 1280*4      =   5120 B
  uint32_t* flags = (uint32_t*)(ws + 153600);  // 8448*4      =  33792 B
  uint16_t* Hx0   = (uint16_t*)(ws + 187392);  // 2*512*320*2 = 655360 B
  uint16_t* Hx1   = (uint16_t*)(ws + 842752);  // 2*512*320*2 = 655360 B

  hipLaunchKernelGGL(prep_kernel, dim3((PREP_HI + 255) / 256), dim3(256), 0,
                     stream, embed, w_ih, b_ih, b_hh, h0, G0p, b1p, flags,
                     Hx0, Hx1);

  void* args[] = { (void*)&x, (void*)&c0, (void*)&w_ih, (void*)&w_hh,
                   (void*)&G0p, (void*)&b1p, (void*)&Hx0, (void*)&Hx1,
                   (void*)&flags, (void*)&out };
  hipLaunchCooperativeKernel((const void*)rnnt_kernel, dim3(256), dim3(320),
                             args, 0, stream);
}

// Round 13
// 686.044 us; speedup vs baseline: 1.1210x; 1.0173x over previous
//
#include <hip/hip_runtime.h>
#include <stdint.h>

// RNN-T prediction network: embed lookup + 2-layer LSTM, U=128, N=512, C=320.
// FP32 in/out; internal GEMMs bf16 MFMA + fp32 accumulate.
// Persistent cooperative kernel, 256 WGs = 16 batch-groups x 16 hidden-groups.
// R17 (FINAL): R13 verbatim — the best harness-verified kernel (694.5us
//      reported / 602us warm dispatch). Locked in after R14-R16 showed the
//      structure is at its floor: R14 half-tick split 665 (regression),
//      R15 pitch-85 617 (regression, raised bank conflicts), R16 isolated
//      load-reorder 602 (neutral). The kernel is latency-bound by the serial
//      recurrence (129 dependent ticks x [GEMM chain + barriers + 2 XCD-L2
//      exchange RTs]), not by HBM (3%) or MFMA (11%) -- the two big wins
//      were coherence-mechanism fixes: R5 removed per-tick buffer_wbl2/inv
//      (1430->641), R8 moved the h-exchange to the XCD's L2 via sc0
//      (655->617). Proven invariants: cooperative grid <= 256 (512 never
//      launches -> silent zeros); flags agent-scope IC atomics only (sc0
//      spin-polls hang); sc0 one-shot data exchange runtime-gated by the
//      fail-safe XCC handshake (falls back to agent/IC if WG->XCD
//      co-location doesn't hold).
//      Schedule per tick:
//        phase A (MFMA on Hl0: Bhh0 + Bih1)    <- no Hl1 dependency
//        poll1 (flag1 from LAST tick ~a tick old -> ~0 wait), B0
//        stage Hl1 + write gates0, B1
//        pw0 -> Hx0 store; phase B (Bhh1 on Hl1) covers ack; drain;
//        publish flag0; write gates1, B2
//        pw1 -> Hx1 store -> drain -> publish flag1 -> out g store
//        prefetch; poll0 (gap ~1 RT); B3; stage Hl0; B4

typedef short short8 __attribute__((ext_vector_type(8)));
typedef float f32x4 __attribute__((ext_vector_type(4)));
typedef unsigned long long u64t;

#define USTEPS 128
#define HSZ    (512*320)
#define GSTEP  (512*320)
#define HGOFF  (128*512*320)
#define CGOFF  (HGOFF + 2*512*320)
#define FLAGSTRIDE 16   // uint32s = 64B per slot

__device__ __forceinline__ uint16_t f2bf(float f) {
  union { float f; uint32_t i; } v; v.f = f;
  uint32_t i = v.i;
  return (uint16_t)((i + 0x7fffu + ((i >> 16) & 1u)) >> 16);
}
__device__ __forceinline__ float rcp_(float x) { return __builtin_amdgcn_rcpf(x); }
__device__ __forceinline__ float sigm(float x) { return rcp_(1.0f + __expf(-x)); }
__device__ __forceinline__ float tanh_(float x) {
  float ax = fabsf(x);
  float e  = __expf(-2.0f * ax);
  float t  = (1.0f - e) * rcp_(1.0f + e);
  return x < 0.0f ? -t : t;
}
__device__ __forceinline__ uint4 cvt8(const float* s) {
  float4 a = ((const float4*)s)[0];
  float4 b = ((const float4*)s)[1];
  uint4 r;
  r.x = (uint32_t)f2bf(a.x) | ((uint32_t)f2bf(a.y) << 16);
  r.y = (uint32_t)f2bf(a.z) | ((uint32_t)f2bf(a.w) << 16);
  r.z = (uint32_t)f2bf(b.x) | ((uint32_t)f2bf(b.y) << 16);
  r.w = (uint32_t)f2bf(b.z) | ((uint32_t)f2bf(b.w) << 16);
  return r;
}
__device__ __forceinline__ short8 loadw8(const float* p) {
  float4 a = ((const float4*)p)[0];
  float4 b = ((const float4*)p)[1];
  short8 r;
  r[0] = (short)f2bf(a.x); r[1] = (short)f2bf(a.y);
  r[2] = (short)f2bf(a.z); r[3] = (short)f2bf(a.w);
  r[4] = (short)f2bf(b.x); r[5] = (short)f2bf(b.y);
  r[6] = (short)f2bf(b.z); r[7] = (short)f2bf(b.w);
  return r;
}

// ---- scope-selectable one-shot data-exchange ops (R8-proven) --------------
__device__ __forceinline__ u64t slowld64(const void* p) {
  return __hip_atomic_load((const u64t*)p, __ATOMIC_RELAXED,
                           __HIP_MEMORY_SCOPE_AGENT);
}
template<bool FAST>
__device__ __forceinline__ u64t exld64(const void* p) {
  if (FAST) {
    u64t r;
    asm volatile("global_load_dwordx2 %0, %1, off sc0" : "=v"(r) : "v"(p));
    return r;
  } else {
    return slowld64(p);
  }
}
template<bool FAST>
__device__ __forceinline__ void exst32(void* p, uint32_t v) {
  if (FAST) {
    asm volatile("global_store_dword %0, %1, off sc0" :: "v"(p), "v"(v) : "memory");
  } else {
    __hip_atomic_store((uint32_t*)p, v, __ATOMIC_RELAXED,
                       __HIP_MEMORY_SCOPE_AGENT);
  }
}
__device__ __forceinline__ void vm_drain() {
  asm volatile("s_waitcnt vmcnt(0)" ::: "memory");
}

// ---------------------------------------------------------------------------
// prep: G0p table, bias1p, flag+xcdtab zeroing, h0 -> bf16 prefill of
// exchange slot 1 for both layers.
// ---------------------------------------------------------------------------
#define PREP_G0   (29 * 1280)
#define PREP_B1   (PREP_G0 + 1280)
#define PREP_FL   (PREP_B1 + 8448)          // 2*4096 flags + 256 xcdtab
#define PREP_HI   (PREP_FL + 2 * 512 * 40)  // 40960 cvt8 items
__global__ void prep_kernel(const float* __restrict__ embed,
                            const float* __restrict__ w_ih,
                            const float* __restrict__ b_ih,
                            const float* __restrict__ b_hh,
                            const float* __restrict__ h0,
                            float* __restrict__ G0p,
                            float* __restrict__ bias1p,
                            uint32_t* __restrict__ flags,
                            uint16_t* __restrict__ Hx0,
                            uint16_t* __restrict__ Hx1) {
  int tid = blockIdx.x * blockDim.x + threadIdx.x;
  if (tid < PREP_G0) {
    int v = tid / 1280, col = tid % 1280;
    int hg = col / 80, idx = col % 80;
    int k = idx >> 2, q = idx & 3;
    int r = q * 320 + hg * 20 + k;
    float acc = b_ih[r] + b_hh[r];
    if (v < 28) {
      const float4* e = (const float4*)(embed + (size_t)v * 320);
      const float4* w = (const float4*)(w_ih + (size_t)r * 320);
#pragma unroll 4
      for (int i = 0; i < 80; ++i) {
        float4 a = e[i], b = w[i];
        acc += a.x * b.x + a.y * b.y + a.z * b.z + a.w * b.w;
      }
    }
    G0p[tid] = acc;
  } else if (tid < PREP_B1) {
    int col = tid - PREP_G0;
    int hg = col / 80, idx = col % 80;
    int k = idx >> 2, q = idx & 3;
    int r = q * 320 + hg * 20 + k;
    bias1p[col] = b_ih[1280 + r] + b_hh[1280 + r];
  } else if (tid < PREP_FL) {
    flags[tid - PREP_B1] = 0;
  } else if (tid < PREP_HI) {
    int id = tid - PREP_FL;              // 0..40959, 8 elements each
    int layer = id / 20480;
    int rem = id - layer * 20480;        // n*40 + c
    int n = rem / 40, c = rem - n * 40;
    const float* src = h0 + (size_t)layer * HSZ + (size_t)n * 320 + c * 8;
    uint16_t* dst = (layer ? Hx1 : Hx0) + HSZ + (size_t)n * 320 + c * 8;
    *(uint4*)dst = cvt8(src);
  }
}

// ---------------------------------------------------------------------------
// main loop body, templated on data-exchange scope (flags always agent/IC)
// ---------------------------------------------------------------------------
template<bool FAST>
__device__ __forceinline__ void run_loop(
    const int* __restrict__ x, const float* __restrict__ c0,
    const float* __restrict__ w_ih, const float* __restrict__ w_hh,
    const float* __restrict__ G0p, const float* __restrict__ bias1p,
    uint16_t* __restrict__ Hx0, uint16_t* __restrict__ Hx1,
    uint32_t* __restrict__ flags, float* __restrict__ out,
    uint16_t* Hl0, uint16_t* Hl1, float* gates0, float* gates1,
    int* ctr0, int* ctr1) {
  const int tid  = threadIdx.x;
  const int wave = tid >> 6;
  const int lane = tid & 63;
  const int quad = lane >> 4;
  const int lm   = lane & 15;
  const int blk  = blockIdx.x;
  const int bg = (blk & 7) * 2 + (blk >> 7);
  const int hg = (blk >> 3) & 15;

  // ---- persistent weight fragments (bf16): wave owns 16 gate-cols
  short8 Bhh0[10], Bih1[10], Bhh1[10];
  {
    int ncol = wave * 16 + lm;       // local col 0..79 (= 4k+q)
    int k = ncol >> 2, q = ncol & 3;
    int r = q * 320 + hg * 20 + k;   // original gate row
    const float* p0 = w_hh + (size_t)r * 320 + quad * 8;
    const float* p1 = w_hh + (size_t)(1280 + r) * 320 + quad * 8;
    const float* pi = w_ih + (size_t)(1280 + r) * 320 + quad * 8;
#pragma unroll
    for (int kk = 0; kk < 10; ++kk) {
      Bhh0[kk] = loadw8(p0 + kk * 32);
      Bhh1[kk] = loadw8(p1 + kk * 32);
      Bih1[kk] = loadw8(pi + kk * 32);
    }
  }
  const float bias1v = bias1p[hg * 80 + wave * 16 + lm];

  // ---- pointwise mapping
  const int un  = tid / 10;
  const int ukp = tid - un * 10;
  const int n_g = bg * 32 + un;
  const int kc  = hg * 20 + ukp * 2;

  // ---- staging address precompute, 8B granularity
  int smc[8], spc[8];
#pragma unroll
  for (int it = 0; it < 8; ++it) {
    int cid = tid + it * 320;        // 0..2559 = 32 rows x 80 chunks(8B)
    int m = cid / 80;
    int c8 = cid - m * 80;
    int c16 = c8 >> 1, h = c8 & 1;
    int p16 = c16 + m; if (p16 >= 40) p16 -= 40;
    smc[it] = m * 320 + c8 * 4;
    spc[it] = m * 320 + p16 * 8 + h * 4;
  }
  const size_t gbase = (size_t)bg * 32 * 320;

  float c0s0 = c0[(size_t)n_g * 320 + kc];
  float c0s1 = c0[(size_t)n_g * 320 + kc + 1];
  float c1s0 = c0[(size_t)(512 + n_g) * 320 + kc];
  float c1s1 = c0[(size_t)(512 + n_g) * 320 + kc + 1];

  uint32_t* flags0  = flags;
  uint32_t* flags1  = flags + 256 * FLAGSTRIDE;
  uint32_t* myflag0 = flags0 + (size_t)(bg * 16 + hg) * FLAGSTRIDE;
  uint32_t* myflag1 = flags1 + (size_t)(bg * 16 + hg) * FLAGSTRIDE;

  // ---- pre-stage Hl0 <- initial h0 (prep slot 1): ALWAYS slow (IC-fresh)
  {
    const uint16_t* s0b = Hx0 + HSZ + gbase;
    u64t r0[8];
#pragma unroll
    for (int it = 0; it < 8; ++it) r0[it] = slowld64(s0b + smc[it]);
    vm_drain();
#pragma unroll
    for (int it = 0; it < 8; ++it) *(u64t*)(Hl0 + spc[it]) = r0[it];
    __syncthreads();
  }

  // ---- prefetch x/G0p row for tick 0
  float4 gxa, gxb;
  {
    const int v = x[n_g];
    const float* gx = G0p + (size_t)v * 1280 + hg * 80 + ukp * 8;
    gxa = ((const float4*)gx)[0];
    gxb = ((const float4*)gx)[1];
  }

#pragma unroll 1
  for (int t = 0; t <= USTEPS; ++t) {
    const bool do0 = (t < USTEPS);   // layer0 computes h0[t]
    const bool do1 = (t >= 1);       // layer1 computes h1[t-1]

    // ---- phase A (Hl0 = h0[t-1]): gates0 = Hl0@Bhh0 ; gates1 += Hl0@Bih1
    f32x4 ag00 = {0.f, 0.f, 0.f, 0.f}, ag01 = {0.f, 0.f, 0.f, 0.f};
    f32x4 ag10 = {bias1v, bias1v, bias1v, bias1v}, ag11 = ag10;
#pragma unroll
    for (int kk = 0; kk < 10; ++kk) {
      int cch = kk * 4 + quad;
      int p0a = cch + lm;      if (p0a >= 40) p0a -= 40;
      int p1a = cch + lm + 16; if (p1a >= 40) p1a -= 40;
      short8 a00 = *(const short8*)(Hl0 + lm * 320 + p0a * 8);
      short8 a01 = *(const short8*)(Hl0 + (lm + 16) * 320 + p1a * 8);
      if (do0) {
        ag00 = __builtin_amdgcn_mfma_f32_16x16x32_bf16(a00, Bhh0[kk], ag00, 0, 0, 0);
        ag01 = __builtin_amdgcn_mfma_f32_16x16x32_bf16(a01, Bhh0[kk], ag01, 0, 0, 0);
      }
      if (do1) {
        ag10 = __builtin_amdgcn_mfma_f32_16x16x32_bf16(a00, Bih1[kk], ag10, 0, 0, 0);
        ag11 = __builtin_amdgcn_mfma_f32_16x16x32_bf16(a01, Bih1[kk], ag11, 0, 0, 0);
      }
    }

    // ---- poll1: h1[t-2] exchange complete. flag1=t was published during
    //      tick t-1's pw1 -> ~a full tick old -> first read satisfies.
    if (do1 && t >= 2 && tid < 16) {
      uint32_t* peer = flags1 + (size_t)(bg * 16 + tid) * FLAGSTRIDE;
      while (__hip_atomic_load(peer, __ATOMIC_RELAXED,
                               __HIP_MEMORY_SCOPE_AGENT) < (uint32_t)t) {
      }
    }
    __syncthreads();                                   // B0

    // ---- stage Hl1 <- Hx1 slot (t&1) (h1[t-2]); t==1 = prep slot (IC)
    if (do1) {
      const uint16_t* s1b = Hx1 + (size_t)(t & 1) * HSZ + gbase;
      u64t r1[8];
      if (FAST && t == 1) {
#pragma unroll
        for (int it = 0; it < 8; ++it) r1[it] = slowld64(s1b + smc[it]);
      } else {
#pragma unroll
        for (int it = 0; it < 8; ++it) r1[it] = exld64<FAST>(s1b + smc[it]);
      }
      vm_drain();
#pragma unroll
      for (int it = 0; it < 8; ++it) *(u64t*)(Hl1 + spc[it]) = r1[it];
    }
    if (do0) {
#pragma unroll
      for (int r = 0; r < 4; ++r) {
        gates0[(quad * 4 + r) * 84 + wave * 16 + lm]      = ag00[r];
        gates0[(16 + quad * 4 + r) * 84 + wave * 16 + lm] = ag01[r];
      }
    }
    __syncthreads();                                   // B1

    // ---- layer 0 pointwise -> h0[t] -> Hx0 (sc0 one-shot store)
    if (do0) {
      const float* gp = gates0 + un * 84 + ukp * 8;
      float i0 = gp[0] + gxa.x, f0 = gp[1] + gxa.y, g0 = gp[2] + gxa.z, o0 = gp[3] + gxa.w;
      float i1 = gp[4] + gxb.x, f1 = gp[5] + gxb.y, g1 = gp[6] + gxb.z, o1 = gp[7] + gxb.w;
      c0s0 = sigm(f0) * c0s0 + sigm(i0) * tanh_(g0);
      c0s1 = sigm(f1) * c0s1 + sigm(i1) * tanh_(g1);
      float ha = sigm(o0) * tanh_(c0s0);
      float hb = sigm(o1) * tanh_(c0s1);
      uint32_t packed = (uint32_t)f2bf(ha) | ((uint32_t)f2bf(hb) << 16);
      exst32<FAST>(Hx0 + (size_t)(t & 1) * HSZ + (size_t)n_g * 320 + kc, packed);
      if (t == USTEPS - 1) {
        *(float2*)(out + HGOFF + (size_t)n_g * 320 + kc) = make_float2(ha, hb);
        *(float2*)(out + CGOFF + (size_t)n_g * 320 + kc) = make_float2(c0s0, c0s1);
      }
    }

    // ---- phase B: gates1 += Hl1@Bhh1 (covers the Hx0 store ack)
    if (do1) {
#pragma unroll
      for (int kk = 0; kk < 10; ++kk) {
        int cch = kk * 4 + quad;
        int p0a = cch + lm;      if (p0a >= 40) p0a -= 40;
        int p1a = cch + lm + 16; if (p1a >= 40) p1a -= 40;
        short8 a10 = *(const short8*)(Hl1 + lm * 320 + p0a * 8);
        short8 a11 = *(const short8*)(Hl1 + (lm + 16) * 320 + p1a * 8);
        ag10 = __builtin_amdgcn_mfma_f32_16x16x32_bf16(a10, Bhh1[kk], ag10, 0, 0, 0);
        ag11 = __builtin_amdgcn_mfma_f32_16x16x32_bf16(a11, Bhh1[kk], ag11, 0, 0, 0);
      }
    }

    // ---- publish flag0: drain (ack arrived under phase B) + LDS counter;
    //      gap to poll0 = B2 + pw1 + prefetch ~ 1 RT.
    if (do0) {
      vm_drain();
      if (lane == 0) {
        int old = atomicAdd(ctr0, 1);
        if ((old % 5) == 4)
          __hip_atomic_store(myflag0, (uint32_t)(t + 1), __ATOMIC_RELAXED,
                             __HIP_MEMORY_SCOPE_AGENT);
      }
    }

    if (do1) {
#pragma unroll
      for (int r = 0; r < 4; ++r) {
        gates1[(quad * 4 + r) * 84 + wave * 16 + lm]      = ag10[r];
        gates1[(16 + quad * 4 + r) * 84 + wave * 16 + lm] = ag11[r];
      }
    }
    __syncthreads();                                   // B2

    // ---- layer 1 pointwise: Hx1 store -> drain -> flag1 publish -> g out
    //      (flag1 is then ~a full tick ahead of its poll next tick)
    if (do1) {
      const int u1 = t - 1;
      const float* gp = gates1 + un * 84 + ukp * 8;
      float i0 = gp[0], f0 = gp[1], g0 = gp[2], o0 = gp[3];
      float i1 = gp[4], f1 = gp[5], g1 = gp[6], o1 = gp[7];
      c1s0 = sigm(f0) * c1s0 + sigm(i0) * tanh_(g0);
      c1s1 = sigm(f1) * c1s1 + sigm(i1) * tanh_(g1);
      float ha = sigm(o0) * tanh_(c1s0);
      float hb = sigm(o1) * tanh_(c1s1);
      uint32_t packed = (uint32_t)f2bf(ha) | ((uint32_t)f2bf(hb) << 16);
      exst32<FAST>(Hx1 + (size_t)((t + 1) & 1) * HSZ + (size_t)n_g * 320 + kc, packed);
      vm_drain();
      if (lane == 0) {
        int old = atomicAdd(ctr1, 1);
        if ((old % 5) == 4)
          __hip_atomic_store(myflag1, (uint32_t)(t + 1), __ATOMIC_RELAXED,
                             __HIP_MEMORY_SCOPE_AGENT);
      }
      *(float2*)(out + (size_t)u1 * GSTEP + (size_t)n_g * 320 + kc) = make_float2(ha, hb);
      if (t == USTEPS) {
        *(float2*)(out + HGOFF + (size_t)(512 + n_g) * 320 + kc) = make_float2(ha, hb);
        *(float2*)(out + CGOFF + (size_t)(512 + n_g) * 320 + kc) = make_float2(c1s0, c1s1);
      }
    }

    // ---- prefetch next tick's x/G0p row
    if (t + 1 < USTEPS) {
      const int v = x[(t + 1) * 512 + n_g];
      const float* gx = G0p + (size_t)v * 1280 + hg * 80 + ukp * 8;
      gxa = ((const float4*)gx)[0];
      gxb = ((const float4*)gx)[1];
    }

    // ---- tick end: poll0 -> stage Hl0 <- h0[t]
    if (t < USTEPS) {
      if (tid < 16) {
        uint32_t* peer = flags0 + (size_t)(bg * 16 + tid) * FLAGSTRIDE;
        while (__hip_atomic_load(peer, __ATOMIC_RELAXED,
                                 __HIP_MEMORY_SCOPE_AGENT) < (uint32_t)(t + 1)) {
        }
      }
      __syncthreads();                                 // B3
      const uint16_t* s0b = Hx0 + (size_t)(t & 1) * HSZ + gbase;
      u64t r0[8];
#pragma unroll
      for (int it = 0; it < 8; ++it) r0[it] = exld64<FAST>(s0b + smc[it]);
      vm_drain();
#pragma unroll
      for (int it = 0; it < 8; ++it) *(u64t*)(Hl0 + spc[it]) = r0[it];
      __syncthreads();                                 // B4
    }
  }
}

// ---------------------------------------------------------------------------
// main persistent kernel: fail-safe XCD handshake, scoped loop
// ---------------------------------------------------------------------------
__global__ void __launch_bounds__(320, 2)
rnnt_kernel(const int* __restrict__ x,
            const float* __restrict__ c0,
            const float* __restrict__ w_ih,
            const float* __restrict__ w_hh,
            const float* __restrict__ G0p,
            const float* __restrict__ bias1p,
            uint16_t* __restrict__ Hx0,
            uint16_t* __restrict__ Hx1,
            uint32_t* __restrict__ flags,
            float* __restrict__ out) {
  __shared__ __align__(16) uint16_t Hl0[32 * 320];
  __shared__ __align__(16) uint16_t Hl1[32 * 320];
  __shared__ __align__(16) float    gates0[32 * 84];
  __shared__ __align__(16) float    gates1[32 * 84];
  __shared__ int ctr0, ctr1;
  __shared__ uint32_t v0sh;

  const int tid = threadIdx.x;
  const int blk = blockIdx.x;
  const int bg = (blk & 7) * 2 + (blk >> 7);
  const int hg = (blk >> 3) & 15;

  // XCC probe: hwreg(id=20, offset=0, size=4) = 20 | (3<<11). Garbage or
  // per-CU-varying reads force the slow path via the checks below (safe).
  const uint32_t xcc = (uint32_t)__builtin_amdgcn_s_getreg((3 << 11) | 20) & 0xffu;
  const uint32_t mine = 0x100u | xcc;
  uint32_t* xcdtab = flags + 8192;

  if (tid == 0) {
    ctr0 = 0; ctr1 = 0;
    __hip_atomic_store(&xcdtab[bg * 16 + hg], mine, __ATOMIC_RELAXED,
                       __HIP_MEMORY_SCOPE_AGENT);
  }
  uint32_t v = 0;
  if (tid < 256) {
    do {
      v = __hip_atomic_load(&xcdtab[tid], __ATOMIC_RELAXED,
                            __HIP_MEMORY_SCOPE_AGENT);
    } while (v == 0u);
    if (tid == 0) v0sh = v;
  }
  __syncthreads();
  const uint32_t v0 = v0sh;
  const int anydiff = __syncthreads_or((tid < 256) ? (int)(v != v0) : 0);
  const int anybad  = __syncthreads_or(
      (tid < 256 && (tid >> 4) == bg) ? (int)(v != mine) : 0);
  const bool fastok = (anydiff != 0) && (anybad == 0);

  if (fastok)
    run_loop<true>(x, c0, w_ih, w_hh, G0p, bias1p, Hx0, Hx1, flags, out,
                   Hl0, Hl1, gates0, gates1, &ctr0, &ctr1);
  else
    run_loop<false>(x, c0, w_ih, w_hh, G0p, bias1p, Hx0, Hx1, flags, out,
                    Hl0, Hl1, gates0, gates1, &ctr0, &ctr1);
}

extern "C" void kernel_launch(void* const* d_in, const int* in_sizes, int n_in,
                              void* d_out, int out_size, void* d_ws, size_t ws_size,
                              hipStream_t stream) {
  (void)in_sizes; (void)n_in; (void)out_size; (void)ws_size;
  const int*   x     = (const int*)d_in[0];
  const float* h0    = (const float*)d_in[1];
  const float* c0    = (const float*)d_in[2];
  const float* embed = (const float*)d_in[3];
  const float* w_ih  = (const float*)d_in[4];
  const float* w_hh  = (const float*)d_in[5];
  const float* b_ih  = (const float*)d_in[6];
  const float* b_hh  = (const float*)d_in[7];
  float* out = (float*)d_out;

  char* ws = (char*)d_ws;
  float*    G0p   = (float*)(ws);              // 29*1280*4   = 148480 B
  float*    b1p   = (float*)(ws + 148480);     // 1280*4      =   5120 B
  uint32_t* flags = (uint32_t*)(ws + 153600);  // 8448*4      =  33792 B
  uint16_t* Hx0   = (uint16_t*)(ws + 187392);  // 2*512*320*2 = 655360 B
  uint16_t* Hx1   = (uint16_t*)(ws + 842752);  // 2*512*320*2 = 655360 B

  hipLaunchKernelGGL(prep_kernel, dim3((PREP_HI + 255) / 256), dim3(256), 0,
                     stream, embed, w_ih, b_ih, b_hh, h0, G0p, b1p, flags,
                     Hx0, Hx1);

  void* args[] = { (void*)&x, (void*)&c0, (void*)&w_ih, (void*)&w_hh,
                   (void*)&G0p, (void*)&b1p, (void*)&Hx0, (void*)&Hx1,
                   (void*)&flags, (void*)&out };
  hipLaunchCooperativeKernel((const void*)rnnt_kernel, dim3(256), dim3(320),
                             args, 0, stream);
}